// Round 7
// baseline (3707.903 us; speedup 1.0000x reference)
//
#include <hip/hip_runtime.h>
#include <hip/hip_bf16.h>

#define NG   8
#define LSZ  256
#define NN   2048
#define KK   30
#define EE   61440
#define IND  1280
#define EMB  256
#define V3   15
#define EAP  156
#define QRM  768
#define QRN  5

#define F32_EPS    5.9604645e-08f
#define F32_EPS2   3.5527137e-15f
#define F32_SAFMIN 1.17549435e-38f

__device__ __forceinline__ float bsumf(float v, float* rbuf){
  int t = threadIdx.x;
  __syncthreads();
  rbuf[t] = v;
  __syncthreads();
  for (int s=128; s>0; s>>=1){
    if (t < s) rbuf[t] += rbuf[t+s];
    __syncthreads();
  }
  float r = rbuf[0];
  __syncthreads();
  return r;
}
__device__ __forceinline__ float gelu_f(float x){
  return 0.5f*x*(1.0f + erff(x*0.70710678f));
}
__device__ __forceinline__ float s_sign(float a, float b){ return (b >= 0.0f) ? fabsf(a) : -fabsf(a); }
__device__ __forceinline__ float slapy2(float x, float y){
  float xa = fabsf(x), ya = fabsf(y);
  float w = fmaxf(xa, ya), z = fminf(xa, ya);
  if (z == 0.0f) return w;
  float t = z/w;
  return w*sqrtf(1.0f + t*t);
}
// LAPACK >=3.10 slartg (f32)
__device__ void slartg(float f, float g, float& c, float& s, float& r){
  const float safmin = F32_SAFMIN;
  const float safmax = 8.5070592e+37f;
  const float rtmin  = 1.0842022e-19f;
  const float rtmax  = 6.5243586e+18f;
  float f1 = fabsf(f), g1 = fabsf(g);
  if (g == 0.0f){ c = 1.0f; s = 0.0f; r = f; }
  else if (f == 0.0f){ c = 0.0f; s = (g >= 0.0f ? 1.0f : -1.0f); r = g1; }
  else {
    if (f1 > rtmin && f1 < rtmax && g1 > rtmin && g1 < rtmax){
      float d = sqrtf(f*f + g*g);
      c = f1/d;
      r = (f >= 0.0f ? d : -d);
      s = g/r;
    } else {
      float u = fminf(safmax, fmaxf(safmin, fmaxf(f1,g1)));
      float fs = f/u, gs = g/u;
      float d = sqrtf(fs*fs + gs*gs);
      c = fabsf(fs)/d;
      r = (f >= 0.0f ? d : -d);
      s = gs/r;
      r = r*u;
    }
  }
}
__device__ void slaev2(float a, float b, float c, float& rt1, float& rt2, float& cs1, float& sn1){
  float sm = a + c, df = a - c, adf = fabsf(df), tb = b + b, ab = fabsf(tb);
  float acmx, acmn;
  if (fabsf(a) > fabsf(c)) { acmx=a; acmn=c; } else { acmx=c; acmn=a; }
  float rt;
  if (adf > ab){ float t = ab/adf; rt = adf*sqrtf(1.0f+t*t); }
  else if (adf < ab){ float t = adf/ab; rt = ab*sqrtf(1.0f+t*t); }
  else rt = ab*sqrtf(2.0f);
  int sgn1;
  if (sm < 0.0f){ rt1 = 0.5f*(sm-rt); sgn1 = -1; rt2 = (acmx/rt1)*acmn - (b/rt1)*b; }
  else if (sm > 0.0f){ rt1 = 0.5f*(sm+rt); sgn1 = 1; rt2 = (acmx/rt1)*acmn - (b/rt1)*b; }
  else { rt1 = 0.5f*rt; rt2 = -0.5f*rt; sgn1 = 1; }
  float cs; int sgn2;
  if (df >= 0.0f){ cs = df + rt; sgn2 = 1; } else { cs = df - rt; sgn2 = -1; }
  float acs = fabsf(cs);
  if (acs > ab){
    float ct = -tb/cs; sn1 = 1.0f/sqrtf(1.0f+ct*ct); cs1 = ct*sn1;
  } else {
    if (ab == 0.0f){ cs1 = 1.0f; sn1 = 0.0f; }
    else { float tn = -cs/tb; cs1 = 1.0f/sqrtf(1.0f+tn*tn); sn1 = tn*cs1; }
  }
  if (sgn1 == sgn2){ float tn = cs1; cs1 = -sn1; sn1 = tn; }
}

// f32 ssytd2('L') + ssteqr('I') for 4x4; returns eigvec of largest eigenvalue + lambda.
__device__ void sym4_quat_f32(float (&a)[4][4], float* q, float* lam){
  float d[4], e[3];
  float tau0 = 0.0f, tau1 = 0.0f;
  float v31 = 0.0f, v41 = 0.0f, v42 = 0.0f;
  {
    float alpha = a[1][0];
    float x1 = a[2][0], x2 = a[3][0];
    float xnorm = sqrtf(x1*x1 + x2*x2);
    if (xnorm == 0.0f){ tau0 = 0.0f; e[0] = alpha; }
    else {
      float beta = -s_sign(slapy2(alpha, xnorm), alpha);
      tau0 = (beta - alpha)/beta;
      float sc = 1.0f/(alpha - beta);
      x1 *= sc; x2 *= sc;
      e[0] = beta;
      float p0 = tau0*(a[1][1] + a[2][1]*x1 + a[3][1]*x2);
      float p1 = tau0*(a[2][1] + a[2][2]*x1 + a[3][2]*x2);
      float p2 = tau0*(a[3][1] + a[3][2]*x1 + a[3][3]*x2);
      float al = -0.5f*tau0*(p0 + p1*x1 + p2*x2);
      p0 += al; p1 += al*x1; p2 += al*x2;
      a[1][1] -= 2.0f*p0;
      a[2][1] -= x1*p0 + p1;
      a[3][1] -= x2*p0 + p2;
      a[2][2] -= 2.0f*x1*p1;
      a[3][2] -= x2*p1 + p2*x1;
      a[3][3] -= 2.0f*x2*p2;
    }
    v31 = x1; v41 = x2;
  }
  {
    float alpha = a[2][1];
    float x1 = a[3][1];
    float xnorm = fabsf(x1);
    if (xnorm == 0.0f){ tau1 = 0.0f; e[1] = alpha; }
    else {
      float beta = -s_sign(slapy2(alpha, xnorm), alpha);
      tau1 = (beta - alpha)/beta;
      x1 *= 1.0f/(alpha - beta);
      e[1] = beta;
      float p0 = tau1*(a[2][2] + a[3][2]*x1);
      float p1 = tau1*(a[3][2] + a[3][3]*x1);
      float al = -0.5f*tau1*(p0 + p1*x1);
      p0 += al; p1 += al*x1;
      a[2][2] -= 2.0f*p0;
      a[3][2] -= x1*p0 + p1;
      a[3][3] -= 2.0f*x1*p1;
    }
    v42 = x1;
  }
  e[2] = a[3][2];
  d[0]=a[0][0]; d[1]=a[1][1]; d[2]=a[2][2]; d[3]=a[3][3];
  float z[4][4] = {{1,0,0,0},{0,1,0,0},{0,0,1,0},{0,0,0,1}};
  const float eps = F32_EPS;
  const float eps2 = F32_EPS2;
  const float safmin = F32_SAFMIN;
  int jtot = 0;
  const int nmaxit = 120;
  int l1 = 0;
  bool fail = false;
  while (!fail){
    if (l1 > 3) break;
    if (l1 > 0) e[l1-1] = 0.0f;
    int lend = 3;
    for (int mm = l1; mm <= 2; ++mm){
      float tst = fabsf(e[mm]);
      if (tst == 0.0f){ lend = mm; break; }
      if (tst <= (sqrtf(fabsf(d[mm]))*sqrtf(fabsf(d[mm+1])))*eps){ e[mm] = 0.0f; lend = mm; break; }
    }
    int l = l1;
    int lsv = l, lendsv = lend;
    l1 = lend + 1;
    if (lend == l) continue;
    float anorm = fabsf(d[l]);
    for (int ii=l+1; ii<=lend; ++ii) anorm = fmaxf(anorm, fabsf(d[ii]));
    for (int ii=l; ii<lend; ++ii)    anorm = fmaxf(anorm, fabsf(e[ii]));
    if (anorm == 0.0f) continue;
    if (fabsf(d[lend]) < fabsf(d[l])){ lend = lsv; l = lendsv; }
    if (lend > l){
      for (;;){
        int m = lend;
        if (l != lend){
          for (int mm=l; mm<=lend-1; ++mm){
            float tst = e[mm]*e[mm];
            if (tst <= (eps2*fabsf(d[mm]))*fabsf(d[mm+1]) + safmin){ m = mm; break; }
          }
        }
        if (m < lend) e[m] = 0.0f;
        float p = d[l];
        if (m == l){
          d[l] = p; ++l;
          if (l <= lend) continue;
          break;
        }
        if (m == l+1){
          float rt1, rt2, c, s;
          slaev2(d[l], e[l], d[l+1], rt1, rt2, c, s);
          #pragma unroll
          for (int r2=0;r2<4;r2++){
            float t_ = z[r2][l+1];
            z[r2][l+1] = c*t_ - s*z[r2][l];
            z[r2][l]   = s*t_ + c*z[r2][l];
          }
          d[l]=rt1; d[l+1]=rt2; e[l]=0.0f;
          l += 2;
          if (l <= lend) continue;
          break;
        }
        if (jtot == nmaxit){ fail = true; break; }
        ++jtot;
        float g = (d[l+1]-p)/(2.0f*e[l]);
        float r_ = slapy2(g, 1.0f);
        g = d[m] - p + e[l]/(g + s_sign(r_, g));
        float s = 1.0f, c = 1.0f;
        p = 0.0f;
        float csv[3], snv[3];
        for (int i=m-1; i>=l; --i){
          float f = s*e[i], b = c*e[i];
          slartg(g, f, c, s, r_);
          if (i != m-1) e[i+1] = r_;
          g = d[i+1] - p;
          r_ = (d[i]-g)*s + 2.0f*c*b;
          p = s*r_;
          d[i+1] = g + p;
          g = c*r_ - b;
          csv[i] = c; snv[i] = -s;
        }
        for (int i=m-1; i>=l; --i){
          float cc = csv[i], ss = snv[i];
          #pragma unroll
          for (int r2=0;r2<4;r2++){
            float t_ = z[r2][i+1];
            z[r2][i+1] = cc*t_ - ss*z[r2][i];
            z[r2][i]   = ss*t_ + cc*z[r2][i];
          }
        }
        d[l] -= p; e[l] = g;
      }
    } else {
      for (;;){
        int m = lend;
        if (l != lend){
          for (int mm=l; mm>=lend+1; --mm){
            float tst = e[mm-1]*e[mm-1];
            if (tst <= (eps2*fabsf(d[mm]))*fabsf(d[mm-1]) + safmin){ m = mm; break; }
          }
        }
        if (m > lend) e[m-1] = 0.0f;
        float p = d[l];
        if (m == l){
          d[l] = p; --l;
          if (l >= lend) continue;
          break;
        }
        if (m == l-1){
          float rt1, rt2, c, s;
          slaev2(d[l-1], e[l-1], d[l], rt1, rt2, c, s);
          #pragma unroll
          for (int r2=0;r2<4;r2++){
            float t_ = z[r2][l];
            z[r2][l]   = c*t_ - s*z[r2][l-1];
            z[r2][l-1] = s*t_ + c*z[r2][l-1];
          }
          d[l-1]=rt1; d[l]=rt2; e[l-1]=0.0f;
          l -= 2;
          if (l >= lend) continue;
          break;
        }
        if (jtot == nmaxit){ fail = true; break; }
        ++jtot;
        float g = (d[l-1]-p)/(2.0f*e[l-1]);
        float r_ = slapy2(g, 1.0f);
        g = d[m] - p + e[l-1]/(g + s_sign(r_, g));
        float s = 1.0f, c = 1.0f;
        p = 0.0f;
        float csv[3], snv[3];
        for (int i=m; i<=l-1; ++i){
          float f = s*e[i], b = c*e[i];
          slartg(g, f, c, s, r_);
          if (i != m) e[i-1] = r_;
          g = d[i] - p;
          r_ = (d[i+1]-g)*s + 2.0f*c*b;
          p = s*r_;
          d[i] = g + p;
          g = c*r_ - b;
          csv[i] = c; snv[i] = s;
        }
        for (int i=m; i<=l-1; ++i){
          float cc = csv[i], ss = snv[i];
          #pragma unroll
          for (int r2=0;r2<4;r2++){
            float t_ = z[r2][i+1];
            z[r2][i+1] = cc*t_ - ss*z[r2][i];
            z[r2][i]   = ss*t_ + cc*z[r2][i];
          }
        }
        d[l] -= p; e[l-1] = g;
      }
    }
  }
  for (int ii=1; ii<4; ++ii){
    int i0 = ii-1, k0 = i0;
    float p = d[i0];
    for (int j2=ii; j2<4; ++j2) if (d[j2] < p){ k0 = j2; p = d[j2]; }
    if (k0 != i0){
      d[k0] = d[i0]; d[i0] = p;
      #pragma unroll
      for (int r2=0;r2<4;r2++){ float t_ = z[r2][i0]; z[r2][i0] = z[r2][k0]; z[r2][k0] = t_; }
    }
  }
  float w0 = z[0][3], w1 = z[1][3], w2 = z[2][3], w3 = z[3][3];
  if (tau1 != 0.0f){
    float dv = w2 + v42*w3;
    w2 -= tau1*dv;
    w3 -= tau1*dv*v42;
  }
  if (tau0 != 0.0f){
    float dv = w1 + v31*w2 + v41*w3;
    w1 -= tau0*dv;
    w2 -= tau0*dv*v31;
    w3 -= tau0*dv*v41;
  }
  q[0]=w0; q[1]=w1; q[2]=w2; q[3]=w3;
  *lam = d[3];
}

__device__ __forceinline__ void atomic_fmax(float* p, float v){
  atomicMax((int*)p, __float_as_int(v));   // valid for v >= 0
}

// ---------------- kernels ----------------
__global__ void fill_kernel(float* __restrict__ p, int nelem, float val){
  int i = blockIdx.x*blockDim.x + threadIdx.x;
  if (i < nelem) p[i] = val;
}

__global__ void rigid_kernel(const float* __restrict__ bb, float* __restrict__ Rg, float* __restrict__ tg){
  int n = blockIdx.x*blockDim.x + threadIdx.x;
  if (n >= NN) return;
  const float* p = bb + (size_t)n*9;
  float nx=p[0],ny=p[1],nz=p[2], cax=p[3],cay=p[4],caz=p[5], cx=p[6],cy=p[7],cz=p[8];
  float e1x=cx-cax, e1y=cy-cay, e1z=cz-caz;
  float n1 = sqrtf(e1x*e1x+e1y*e1y+e1z*e1z);
  e1x/=n1; e1y/=n1; e1z/=n1;
  float ux=nx-cax, uy=ny-cay, uz=nz-caz;
  float du = ux*e1x+uy*e1y+uz*e1z;
  float e2x=ux-du*e1x, e2y=uy-du*e1y, e2z=uz-du*e1z;
  float n2 = sqrtf(e2x*e2x+e2y*e2y+e2z*e2z);
  e2x/=n2; e2y/=n2; e2z/=n2;
  float e3x=e1y*e2z-e1z*e2y, e3y=e1z*e2x-e1x*e2z, e3z=e1x*e2y-e1y*e2x;
  float* R = Rg + (size_t)n*9;
  R[0]=e1x; R[1]=e2x; R[2]=e3x;
  R[3]=e1y; R[4]=e2y; R[5]=e3y;
  R[6]=e1z; R[7]=e2z; R[8]=e3z;
  tg[(size_t)n*3+0]=cax; tg[(size_t)n*3+1]=cay; tg[(size_t)n*3+2]=caz;
}

__global__ __launch_bounds__(256) void ln_kernel(const float* __restrict__ x,
    const float* __restrict__ g, const float* __restrict__ b, float* __restrict__ xln){
  int n = blockIdx.x, t = threadIdx.x;
  __shared__ float rbuf[256];
  float v[5];
  float s = 0.0f;
  #pragma unroll
  for (int i=0;i<5;i++){ v[i] = x[(size_t)n*IND + t + i*256]; s += v[i]; }
  float mu = bsumf(s, rbuf)*(1.0f/IND);
  float pv = 0.0f;
  #pragma unroll
  for (int i=0;i<5;i++){ float dd = v[i]-mu; pv += dd*dd; }
  float var = bsumf(pv, rbuf)*(1.0f/IND);
  float rs = 1.0f/sqrtf(var + 1e-5f);
  #pragma unroll
  for (int i=0;i<5;i++){
    int k = t + i*256;
    xln[(size_t)n*IND + k] = g[k]*((v[i]-mu)*rs) + b[k];
  }
}

__global__ __launch_bounds__(256) void emb0_kernel(const float* __restrict__ xln,
    const float* __restrict__ W, const float* __restrict__ bias, float* __restrict__ emb){
  int n0 = blockIdx.x*8, j = threadIdx.x;
  float acc[8];
  #pragma unroll
  for (int i=0;i<8;i++) acc[i] = bias[j];
  for (int k=0;k<IND;k+=4){
    float w0=W[(size_t)(k+0)*EMB+j], w1=W[(size_t)(k+1)*EMB+j], w2=W[(size_t)(k+2)*EMB+j], w3=W[(size_t)(k+3)*EMB+j];
    #pragma unroll
    for (int i=0;i<8;i++){
      const float* xp = xln + (size_t)(n0+i)*IND + k;
      acc[i] += xp[0]*w0 + xp[1]*w1 + xp[2]*w2 + xp[3]*w3;
    }
  }
  #pragma unroll
  for (int i=0;i<8;i++) emb[(size_t)(n0+i)*EMB + j] = acc[i];
}

__global__ __launch_bounds__(64) void edge_kernel(const float* __restrict__ bb,
    const float* __restrict__ Rg, const float* __restrict__ tg,
    const int* __restrict__ col, float* __restrict__ Redge, float* __restrict__ eattr,
    float* __restrict__ dchk){
  int e = blockIdx.x*64 + threadIdx.x;
  if (e >= EE) return;
  int i = e/KK;
  int jn = col[e];
  float Ri[9], Rj[9];
  #pragma unroll
  for (int a=0;a<9;a++){ Ri[a]=Rg[(size_t)i*9+a]; Rj[a]=Rg[(size_t)jn*9+a]; }
  float dt0 = tg[(size_t)jn*3+0]-tg[(size_t)i*3+0];
  float dt1 = tg[(size_t)jn*3+1]-tg[(size_t)i*3+1];
  float dt2 = tg[(size_t)jn*3+2]-tg[(size_t)i*3+2];
  float Re[9];
  #pragma unroll
  for (int a=0;a<3;a++){
    #pragma unroll
    for (int c=0;c<3;c++)
      Re[a*3+c] = Ri[0+a]*Rj[0+c] + Ri[3+a]*Rj[3+c] + Ri[6+a]*Rj[6+c];
  }
  float te0 = Ri[0]*dt0 + Ri[3]*dt1 + Ri[6]*dt2;
  float te1 = Ri[1]*dt0 + Ri[4]*dt1 + Ri[7]*dt2;
  float te2 = Ri[2]*dt0 + Ri[5]*dt1 + Ri[8]*dt2;
  float xx=Re[0], xy=Re[1], xz=Re[2], yx=Re[3], yy=Re[4], yz=Re[5], zx=Re[6], zy=Re[7], zz=Re[8];
  float km[4][4];
  km[0][0]=(xx+yy+zz)/3.0f; km[0][1]=(zy-yz)/3.0f;    km[0][2]=(xz-zx)/3.0f;    km[0][3]=(yx-xy)/3.0f;
  km[1][0]=km[0][1];        km[1][1]=(xx-yy-zz)/3.0f; km[1][2]=(xy+yx)/3.0f;    km[1][3]=(xz+zx)/3.0f;
  km[2][0]=km[0][2];        km[2][1]=km[1][2];        km[2][2]=(yy-xx-zz)/3.0f; km[2][3]=(yz+zy)/3.0f;
  km[3][0]=km[0][3];        km[3][1]=km[1][3];        km[3][2]=km[2][3];        km[3][3]=(zz-xx-yy)/3.0f;
  float ks[4][4];
  #pragma unroll
  for (int a=0;a<4;a++)
    #pragma unroll
    for (int b2=0;b2<4;b2++) ks[a][b2] = km[a][b2];
  float q[4], lam;
  sym4_quat_f32(km, q, &lam);
  // validity probe: |K q - lam q|_inf and |q|^2-1
  {
    float res = 0.0f, nq = 0.0f;
    #pragma unroll
    for (int a=0;a<4;a++){
      float kv = ks[a][0]*q[0] + ks[a][1]*q[1] + ks[a][2]*q[2] + ks[a][3]*q[3];
      res = fmaxf(res, fabsf(kv - lam*q[a]));
      nq += q[a]*q[a];
    }
    res = fmaxf(res, fabsf(nq - 1.0f));
    atomic_fmax(&dchk[0], res);
  }
  float* ea = eattr + (size_t)e*EAP;
  ea[0]=q[0]; ea[1]=q[1]; ea[2]=q[2]; ea[3]=q[3];
  ea[4]=te0;  ea[5]=te1;  ea[6]=te2;
  int cd = i - jn; if (cd < 0) cd = -cd;
  ea[7] = logf((float)cd + 1.0f);
  ea[8] = logf(sqrtf(te0*te0+te1*te1+te2*te2) + 1e-8f);
  const float* bi = bb + (size_t)i*9;
  const float* bj = bb + (size_t)jn*9;
  int idx = 9;
  #pragma unroll
  for (int a=0;a<3;a++){
    float ax=bi[a*3+0], ay=bi[a*3+1], az=bi[a*3+2];
    #pragma unroll
    for (int b2=0;b2<3;b2++){
      float dx=ax-bj[b2*3+0], dy=ay-bj[b2*3+1], dz=az-bj[b2*3+2];
      float dd = sqrtf(fmaxf(dx*dx+dy*dy+dz*dz, 1e-12f));
      #pragma unroll
      for (int kb=0;kb<16;kb++){
        float muv = 1.3333334f*(float)kb;
        float df = dd - muv;
        ea[idx] = expf(-0.5f*df*df);
        idx++;
      }
    }
  }
  #pragma unroll
  for (int a=0;a<9;a++) Redge[(size_t)e*9+a] = Re[a];
}

__global__ void vjr_kernel(const float* __restrict__ Redge, const float* __restrict__ v_in,
    const int* __restrict__ col, float* __restrict__ vjrg){
  int idx = blockIdx.x*blockDim.x + threadIdx.x;
  if (idx >= EE*V3) return;
  int e = idx/V3, r = idx - e*V3;
  int m = r/3, ii = r - m*3;
  int cj = col[e];
  const float* Rp = Redge + (size_t)e*9;
  const float* vp = v_in + (size_t)cj*V3 + m*3;
  vjrg[(size_t)e*16 + r] = Rp[ii*3+0]*vp[0] + Rp[ii*3+1]*vp[1] + Rp[ii*3+2]*vp[2];
}

// feat layout: [x_i 0:256 | x_j 256:512 | v_i 512:527 | vj_rot 527:542 | v_i-vj_rot 542:557 | edge_attr 557:710]
__global__ __launch_bounds__(256) void h1_kernel(
    const float* __restrict__ emb_in, const float* __restrict__ v_in,
    const float* __restrict__ vjrg, const float* __restrict__ eattr,
    const int* __restrict__ col,
    const float* __restrict__ W1, const float* __restrict__ b1,
    float* __restrict__ h1g){
  int n = blockIdx.x, j = threadIdx.x;
  size_t e0 = (size_t)n*KK;
  float csh = b1[j];
  {
    const float* xi = emb_in + (size_t)n*EMB;
    for (int k=0;k<EMB;k+=4){
      float w0=W1[(size_t)(k+0)*EMB+j], w1=W1[(size_t)(k+1)*EMB+j], w2=W1[(size_t)(k+2)*EMB+j], w3=W1[(size_t)(k+3)*EMB+j];
      csh += xi[k+0]*w0 + xi[k+1]*w1 + xi[k+2]*w2 + xi[k+3]*w3;
    }
    const float* vi = v_in + (size_t)n*V3;
    #pragma unroll
    for (int r=0;r<V3;r++) csh += vi[r]*(W1[(size_t)(512+r)*EMB+j] + W1[(size_t)(542+r)*EMB+j]);
  }
  float acc[KK];
  #pragma unroll
  for (int e=0;e<KK;e++) acc[e] = csh;
  #pragma unroll
  for (int eg=0; eg<KK; eg+=15){
    size_t cb[15];
    #pragma unroll
    for (int qq=0;qq<15;qq++) cb[qq] = (size_t)col[e0+eg+qq]*EMB;
    for (int k=0;k<EMB;k+=4){
      float w0=W1[(size_t)(256+k)*EMB+j], w1=W1[(size_t)(257+k)*EMB+j], w2=W1[(size_t)(258+k)*EMB+j], w3=W1[(size_t)(259+k)*EMB+j];
      #pragma unroll
      for (int qq=0;qq<15;qq++){
        const float* xp = emb_in + cb[qq] + k;
        acc[eg+qq] += xp[0]*w0 + xp[1]*w1 + xp[2]*w2 + xp[3]*w3;
      }
    }
  }
  {
    float wv[V3];
    #pragma unroll
    for (int r=0;r<V3;r++) wv[r] = W1[(size_t)(527+r)*EMB+j] - W1[(size_t)(542+r)*EMB+j];
    #pragma unroll
    for (int e=0;e<KK;e++){
      const float* vp = vjrg + (e0+e)*16;
      float a = acc[e];
      #pragma unroll
      for (int r=0;r<V3;r++) a += vp[r]*wv[r];
      acc[e] = a;
    }
  }
  #pragma unroll
  for (int eg=0; eg<KK; eg+=15){
    for (int k=0;k<152;k+=4){
      float w0=W1[(size_t)(557+k)*EMB+j], w1=W1[(size_t)(558+k)*EMB+j], w2=W1[(size_t)(559+k)*EMB+j], w3=W1[(size_t)(560+k)*EMB+j];
      #pragma unroll
      for (int qq=0;qq<15;qq++){
        const float* ap = eattr + (e0+eg+qq)*EAP + k;
        acc[eg+qq] += ap[0]*w0 + ap[1]*w1 + ap[2]*w2 + ap[3]*w3;
      }
    }
    float wl = W1[(size_t)709*EMB+j];
    #pragma unroll
    for (int qq=0;qq<15;qq++) acc[eg+qq] += eattr[(e0+eg+qq)*EAP + 152]*wl;
  }
  #pragma unroll
  for (int e=0;e<KK;e++) h1g[(e0+e)*EMB + j] = gelu_f(acc[e]);
}

__global__ __launch_bounds__(256) void h2_kernel(
    const float* __restrict__ emb_in,
    const float* __restrict__ h1g,
    const float* __restrict__ W2, const float* __restrict__ b2,
    const float* __restrict__ W3, const float* __restrict__ b3,
    const float* __restrict__ lng, const float* __restrict__ lnb,
    float* __restrict__ emb_out){
  int n = blockIdx.x, j = threadIdx.x;
  __shared__ float sbuf[EMB];
  __shared__ float rbuf[256];
  size_t e0 = (size_t)n*KK;
  float acc[KK];
  #pragma unroll
  for (int e=0;e<KK;e++) acc[e] = b2[j];
  #pragma unroll
  for (int eg=0; eg<KK; eg+=15){
    for (int k=0;k<EMB;k+=4){
      float w0=W2[(size_t)(k+0)*EMB+j], w1=W2[(size_t)(k+1)*EMB+j], w2=W2[(size_t)(k+2)*EMB+j], w3=W2[(size_t)(k+3)*EMB+j];
      #pragma unroll
      for (int qq=0;qq<15;qq++){
        const float* hp = h1g + (e0+eg+qq)*EMB + k;
        acc[eg+qq] += hp[0]*w0 + hp[1]*w1 + hp[2]*w2 + hp[3]*w3;
      }
    }
  }
  float s = 0.0f;
  #pragma unroll
  for (int e=0;e<KK;e++) s += gelu_f(acc[e]);
  sbuf[j] = s;
  __syncthreads();
  float ag = 0.0f;
  for (int k=0;k<EMB;k+=4){
    float4 s4 = *(const float4*)&sbuf[k];
    ag += s4.x*W3[(size_t)(k+0)*EMB+j] + s4.y*W3[(size_t)(k+1)*EMB+j]
        + s4.z*W3[(size_t)(k+2)*EMB+j] + s4.w*W3[(size_t)(k+3)*EMB+j];
  }
  ag = ag*(1.0f/30.0f) + b3[j];
  float u = emb_in[(size_t)n*EMB+j] + ag;
  float mu = bsumf(u, rbuf)*(1.0f/EMB);
  float dl = u - mu;
  float var = bsumf(dl*dl, rbuf)*(1.0f/EMB);
  float rs = 1.0f/sqrtf(var + 1e-5f);
  float y = lng[j]*dl*rs + lnb[j];
  emb_out[(size_t)n*EMB+j] = y;
}

// Fused vu + f32 sgeqr2/sorg2r per graph (raw LAPACK signs) + validity probe.
__global__ __launch_bounds__(256) void vu_qr_kernel(
    const float* __restrict__ emb_new, const float* __restrict__ v_in,
    const float* __restrict__ vW, float* __restrict__ vout, float* __restrict__ dchk){
  int g = blockIdx.x, t = threadIdx.x;
  __shared__ float A[QRM*QRN];
  __shared__ float Asave[QRM*QRN];
  __shared__ float Rsave[QRN*QRN];
  __shared__ float meanv[V3];
  __shared__ float taus[QRN];
  __shared__ float betas[QRN];
  __shared__ float sh[2];
  int n = g*LSZ + t;
  const float* em = emb_new + (size_t)n*EMB;
  const float* vi = v_in + (size_t)n*V3;
  float a[V3];
  #pragma unroll
  for (int j=0;j<V3;j++) a[j] = vi[j];
  for (int k=0;k<EMB;k++){
    float e = em[k];
    #pragma unroll
    for (int j=0;j<V3;j++) a[j] += e*vW[k*V3+j];
  }
  #pragma unroll
  for (int r=0;r<V3;r++){
    float vv = vi[r];
    #pragma unroll
    for (int j=0;j<V3;j++) a[j] += vv*vW[(EMB+r)*V3+j];
  }
  #pragma unroll
  for (int j=0;j<V3;j++) A[t*V3+j] = a[j];
  __syncthreads();
  if (t < V3){
    float s = 0.0f;
    for (int l0=0;l0<LSZ;l0++) s += A[l0*V3+t];
    meanv[t] = s/(float)LSZ;
  }
  __syncthreads();
  #pragma unroll
  for (int j=0;j<V3;j++){
    A[t*V3+j] -= meanv[j];
    Asave[t*V3+j] = A[t*V3+j];
  }
  __syncthreads();
  // ---- sgeqr2 ----
  for (int i=0;i<QRN;i++){
    if (t == 0){
      float s0=0,s1=0,s2=0,s3=0;
      int r=i+1;
      for (; r+3<QRM; r+=4){
        float x0=A[r*QRN+i], x1=A[(r+1)*QRN+i], x2=A[(r+2)*QRN+i], x3=A[(r+3)*QRN+i];
        s0+=x0*x0; s1+=x1*x1; s2+=x2*x2; s3+=x3*x3;
      }
      for (; r<QRM; r++){ float x=A[r*QRN+i]; s0+=x*x; }
      float xn2 = (s0+s1)+(s2+s3);
      float alpha = A[i*QRN+i];
      float taui = 0.0f, sc = 1.0f, beta = alpha;
      if (xn2 != 0.0f){
        beta = -s_sign(slapy2(alpha, sqrtf(xn2)), alpha);
        taui = (beta - alpha)/beta;
        sc = 1.0f/(alpha - beta);
      }
      taus[i] = taui; sh[0] = sc; betas[i] = beta;
    }
    __syncthreads();
    {
      float sc = sh[0];
      for (int r=i+1+t; r<QRM; r+=256) A[r*QRN+i] *= sc;
    }
    __syncthreads();
    for (int j=i+1;j<QRN;j++){
      if (t == 0){
        float s0=A[i*QRN+j], s1=0,s2=0,s3=0;
        int r=i+1;
        for (; r+3<QRM; r+=4){
          s0 += A[r*QRN+i]*A[r*QRN+j];
          s1 += A[(r+1)*QRN+i]*A[(r+1)*QRN+j];
          s2 += A[(r+2)*QRN+i]*A[(r+2)*QRN+j];
          s3 += A[(r+3)*QRN+i]*A[(r+3)*QRN+j];
        }
        for (; r<QRM; r++) s0 += A[r*QRN+i]*A[r*QRN+j];
        sh[0] = taus[i]*((s0+s1)+(s2+s3));
      }
      __syncthreads();
      {
        float w = sh[0];
        for (int r=i+t; r<QRM; r+=256){
          float vr = (r==i) ? 1.0f : A[r*QRN+i];
          A[r*QRN+j] -= w*vr;
        }
      }
      __syncthreads();
    }
  }
  if (t == 0){
    for (int k2=0;k2<QRN;k2++)
      for (int j2=0;j2<QRN;j2++)
        Rsave[k2*QRN+j2] = (j2 < k2) ? 0.0f : ((j2==k2) ? betas[k2] : A[k2*QRN+j2]);
  }
  __syncthreads();
  // ---- sorg2r ----
  for (int i=QRN-1;i>=0;i--){
    for (int j=i+1;j<QRN;j++){
      if (t == 0){
        float s0=A[i*QRN+j], s1=0,s2=0,s3=0;
        int r=i+1;
        for (; r+3<QRM; r+=4){
          s0 += A[r*QRN+i]*A[r*QRN+j];
          s1 += A[(r+1)*QRN+i]*A[(r+1)*QRN+j];
          s2 += A[(r+2)*QRN+i]*A[(r+2)*QRN+j];
          s3 += A[(r+3)*QRN+i]*A[(r+3)*QRN+j];
        }
        for (; r<QRM; r++) s0 += A[r*QRN+i]*A[r*QRN+j];
        sh[0] = taus[i]*((s0+s1)+(s2+s3));
      }
      __syncthreads();
      {
        float w = sh[0];
        for (int r=i+t; r<QRM; r+=256){
          float vr = (r==i) ? 1.0f : A[r*QRN+i];
          A[r*QRN+j] -= w*vr;
        }
      }
      __syncthreads();
    }
    {
      float taui = taus[i];
      for (int r=i+1+t; r<QRM; r+=256) A[r*QRN+i] *= -taui;
    }
    __syncthreads();
    if (t == 0) A[i*QRN+i] = 1.0f - taus[i];
    if (t < i) A[t*QRN+i] = 0.0f;
    __syncthreads();
  }
  // validity probe (f64 accumulation over f32 data)
  if (t == 0){
    float D = 0.0f;
    for (int a2=0;a2<QRN;a2++)
      for (int b2=a2;b2<QRN;b2++){
        double dot = 0.0;
        for (int r=0;r<QRM;r++) dot += (double)A[r*QRN+a2]*(double)A[r*QRN+b2];
        D = fmaxf(D, (float)fabs(dot - (a2==b2 ? 1.0 : 0.0)));
      }
    for (int r=0;r<QRM;r++)
      for (int j2=0;j2<QRN;j2++){
        double rec = 0.0;
        for (int k2=0;k2<=j2;k2++) rec += (double)A[r*QRN+k2]*(double)Rsave[k2*QRN+j2];
        D = fmaxf(D, (float)fabs(rec - (double)Asave[r*QRN+j2]));
      }
    atomic_fmax(&dchk[1], D);
  }
  for (int idx=t; idx<QRM*QRN; idx+=256)
    vout[(size_t)g*LSZ*V3 + idx] = 16.0f*A[idx];
}

__global__ __launch_bounds__(256) void final_kernel(const float* __restrict__ embf,
    const float* __restrict__ vf, const float* __restrict__ Rg,
    const float* __restrict__ dchk, float* __restrict__ out){
  int n = blockIdx.x, t = threadIdx.x;
  out[(size_t)n*EMB + t] = embf[(size_t)n*EMB + t];
  if (t < V3){
    int m = t/3, ii = t - m*3;
    const float* Rp = Rg + (size_t)n*9;
    const float* vp = vf + (size_t)n*V3 + m*3;
    float val = Rp[ii*3+0]*vp[0] + Rp[ii*3+1]*vp[1] + Rp[ii*3+2]*vp[2];
    if (n == 0 && t == 0){
      float S = fmaxf(dchk[0], dchk[1]);
      if (S > 1e-3f) val = 4096.0f*fminf(S, 10.0f);   // validity-failure signal
    }
    out[(size_t)NN*EMB + (size_t)n*V3 + t] = val;
  }
}

// ---------------- host ----------------
extern "C" void kernel_launch(void* const* d_in, const int* in_sizes, int n_in,
                              void* d_out, int out_size, void* d_ws, size_t ws_size,
                              hipStream_t stream){
  (void)in_sizes; (void)n_in; (void)out_size; (void)ws_size;
  const float* x       = (const float*)d_in[0];
  const float* bb      = (const float*)d_in[1];
  const float* in_ln_g = (const float*)d_in[2];
  const float* in_ln_b = (const float*)d_in[3];
  const float* in_W    = (const float*)d_in[4];
  const float* in_b    = (const float*)d_in[5];
  const float* msg_W1  = (const float*)d_in[6];
  const float* msg_b1  = (const float*)d_in[7];
  const float* msg_W2  = (const float*)d_in[8];
  const float* msg_b2  = (const float*)d_in[9];
  const float* msg_W3  = (const float*)d_in[10];
  const float* msg_b3  = (const float*)d_in[11];
  const float* vect_W  = (const float*)d_in[12];
  const float* ln_g    = (const float*)d_in[13];
  const float* ln_b    = (const float*)d_in[14];
  const int*   col     = (const int*)d_in[16];

  char* p = (char*)d_ws;
  auto alloc = [&](size_t bytes)->void*{ void* r = (void*)p; p += (bytes + 255) & ~(size_t)255; return r; };
  float*  Rg    = (float*) alloc((size_t)NN*9*4);
  float*  tg    = (float*) alloc((size_t)NN*3*4);
  float*  xln   = (float*) alloc((size_t)NN*IND*4);
  float*  eA    = (float*) alloc((size_t)NN*EMB*4);
  float*  eB    = (float*) alloc((size_t)NN*EMB*4);
  float*  vA    = (float*) alloc((size_t)NN*V3*4);
  float*  vB    = (float*) alloc((size_t)NN*V3*4);
  float*  Redge = (float*) alloc((size_t)EE*9*4);
  float*  eattr = (float*) alloc((size_t)EE*EAP*4);
  float*  vjrg  = (float*) alloc((size_t)EE*16*4);
  float*  h1g   = (float*) alloc((size_t)EE*EMB*4);
  float*  dchk  = (float*) alloc(256);

  const int NV = NN*V3;
  fill_kernel<<<(NV+255)/256, 256, 0, stream>>>(vA, NV, 0.0f);
  fill_kernel<<<1, 64, 0, stream>>>(dchk, 2, 0.0f);
  rigid_kernel<<<(NN+63)/64, 64, 0, stream>>>(bb, Rg, tg);
  ln_kernel<<<NN, 256, 0, stream>>>(x, in_ln_g, in_ln_b, xln);
  emb0_kernel<<<NN/8, 256, 0, stream>>>(xln, in_W, in_b, eA);
  edge_kernel<<<(EE+63)/64, 64, 0, stream>>>(bb, Rg, tg, col, Redge, eattr, dchk);

  float* ein = eA; float* eout = eB; float* vin = vA; float* vout = vB;
  for (int l=0; l<3; ++l){
    vjr_kernel<<<(EE*V3+255)/256, 256, 0, stream>>>(Redge, vin, col, vjrg);
    h1_kernel<<<NN, 256, 0, stream>>>(ein, vin, vjrg, eattr, col,
        msg_W1 + (size_t)l*710*EMB, msg_b1 + (size_t)l*EMB, h1g);
    h2_kernel<<<NN, 256, 0, stream>>>(ein, h1g,
        msg_W2 + (size_t)l*EMB*EMB, msg_b2 + (size_t)l*EMB,
        msg_W3 + (size_t)l*EMB*EMB, msg_b3 + (size_t)l*EMB,
        ln_g + (size_t)l*EMB, ln_b + (size_t)l*EMB, eout);
    vu_qr_kernel<<<NG, 256, 0, stream>>>(eout, vin,
        vect_W + (size_t)l*(EMB+V3)*V3, vout, dchk);
    float* tmp = ein; ein = eout; eout = tmp;
    tmp = vin; vin = vout; vout = tmp;
  }
  final_kernel<<<NN, 256, 0, stream>>>(ein, vin, Rg, dchk, (float*)d_out);
}

// Round 8
// 2574.813 us; speedup vs baseline: 1.4401x; 1.4401x over previous
//
#include <hip/hip_runtime.h>
#include <hip/hip_bf16.h>

#define NG   8
#define LSZ  256
#define NN   2048
#define KK   30
#define EE   61440
#define IND  1280
#define EMB  256
#define V3   15
#define EAP  156
#define QRM  768
#define QRN  5

#define F32_EPS    5.9604645e-08f
#define F32_EPS2   3.5527137e-15f
#define F32_SAFMIN 1.17549435e-38f

__device__ __forceinline__ float bsumf(float v, float* rbuf){
  int t = threadIdx.x;
  __syncthreads();
  rbuf[t] = v;
  __syncthreads();
  for (int s=128; s>0; s>>=1){
    if (t < s) rbuf[t] += rbuf[t+s];
    __syncthreads();
  }
  float r = rbuf[0];
  __syncthreads();
  return r;
}
__device__ __forceinline__ float gelu_f(float x){
  return 0.5f*x*(1.0f + erff(x*0.70710678f));
}
__device__ __forceinline__ float s_sign(float a, float b){ return (b >= 0.0f) ? fabsf(a) : -fabsf(a); }
__device__ __forceinline__ float slapy2(float x, float y){
  float xa = fabsf(x), ya = fabsf(y);
  float w = fmaxf(xa, ya), z = fminf(xa, ya);
  if (z == 0.0f) return w;
  float t = z/w;
  return w*sqrtf(1.0f + t*t);
}
// LAPACK >=3.10 slartg (f32)
__device__ void slartg(float f, float g, float& c, float& s, float& r){
  const float safmin = F32_SAFMIN;
  const float safmax = 8.5070592e+37f;
  const float rtmin  = 1.0842022e-19f;
  const float rtmax  = 6.5243586e+18f;
  float f1 = fabsf(f), g1 = fabsf(g);
  if (g == 0.0f){ c = 1.0f; s = 0.0f; r = f; }
  else if (f == 0.0f){ c = 0.0f; s = (g >= 0.0f ? 1.0f : -1.0f); r = g1; }
  else {
    if (f1 > rtmin && f1 < rtmax && g1 > rtmin && g1 < rtmax){
      float d = sqrtf(f*f + g*g);
      c = f1/d;
      r = (f >= 0.0f ? d : -d);
      s = g/r;
    } else {
      float u = fminf(safmax, fmaxf(safmin, fmaxf(f1,g1)));
      float fs = f/u, gs = g/u;
      float d = sqrtf(fs*fs + gs*gs);
      c = fabsf(fs)/d;
      r = (f >= 0.0f ? d : -d);
      s = gs/r;
      r = r*u;
    }
  }
}
__device__ void slaev2(float a, float b, float c, float& rt1, float& rt2, float& cs1, float& sn1){
  float sm = a + c, df = a - c, adf = fabsf(df), tb = b + b, ab = fabsf(tb);
  float acmx, acmn;
  if (fabsf(a) > fabsf(c)) { acmx=a; acmn=c; } else { acmx=c; acmn=a; }
  float rt;
  if (adf > ab){ float t = ab/adf; rt = adf*sqrtf(1.0f+t*t); }
  else if (adf < ab){ float t = adf/ab; rt = ab*sqrtf(1.0f+t*t); }
  else rt = ab*sqrtf(2.0f);
  int sgn1;
  if (sm < 0.0f){ rt1 = 0.5f*(sm-rt); sgn1 = -1; rt2 = (acmx/rt1)*acmn - (b/rt1)*b; }
  else if (sm > 0.0f){ rt1 = 0.5f*(sm+rt); sgn1 = 1; rt2 = (acmx/rt1)*acmn - (b/rt1)*b; }
  else { rt1 = 0.5f*rt; rt2 = -0.5f*rt; sgn1 = 1; }
  float cs; int sgn2;
  if (df >= 0.0f){ cs = df + rt; sgn2 = 1; } else { cs = df - rt; sgn2 = -1; }
  float acs = fabsf(cs);
  if (acs > ab){
    float ct = -tb/cs; sn1 = 1.0f/sqrtf(1.0f+ct*ct); cs1 = ct*sn1;
  } else {
    if (ab == 0.0f){ cs1 = 1.0f; sn1 = 0.0f; }
    else { float tn = -cs/tb; cs1 = 1.0f/sqrtf(1.0f+tn*tn); sn1 = tn*cs1; }
  }
  if (sgn1 == sgn2){ float tn = cs1; cs1 = -sn1; sn1 = tn; }
}

// f32 ssytd2('L') + ssteqr('I') for 4x4; returns eigvec of largest eigenvalue.
__device__ void sym4_quat_f32(float (&a)[4][4], float* q){
  float d[4], e[3];
  float tau0 = 0.0f, tau1 = 0.0f;
  float v31 = 0.0f, v41 = 0.0f, v42 = 0.0f;
  {
    float alpha = a[1][0];
    float x1 = a[2][0], x2 = a[3][0];
    float xnorm = sqrtf(x1*x1 + x2*x2);
    if (xnorm == 0.0f){ tau0 = 0.0f; e[0] = alpha; }
    else {
      float beta = -s_sign(slapy2(alpha, xnorm), alpha);
      tau0 = (beta - alpha)/beta;
      float sc = 1.0f/(alpha - beta);
      x1 *= sc; x2 *= sc;
      e[0] = beta;
      float p0 = tau0*(a[1][1] + a[2][1]*x1 + a[3][1]*x2);
      float p1 = tau0*(a[2][1] + a[2][2]*x1 + a[3][2]*x2);
      float p2 = tau0*(a[3][1] + a[3][2]*x1 + a[3][3]*x2);
      float al = -0.5f*tau0*(p0 + p1*x1 + p2*x2);
      p0 += al; p1 += al*x1; p2 += al*x2;
      a[1][1] -= 2.0f*p0;
      a[2][1] -= x1*p0 + p1;
      a[3][1] -= x2*p0 + p2;
      a[2][2] -= 2.0f*x1*p1;
      a[3][2] -= x2*p1 + p2*x1;
      a[3][3] -= 2.0f*x2*p2;
    }
    v31 = x1; v41 = x2;
  }
  {
    float alpha = a[2][1];
    float x1 = a[3][1];
    float xnorm = fabsf(x1);
    if (xnorm == 0.0f){ tau1 = 0.0f; e[1] = alpha; }
    else {
      float beta = -s_sign(slapy2(alpha, xnorm), alpha);
      tau1 = (beta - alpha)/beta;
      x1 *= 1.0f/(alpha - beta);
      e[1] = beta;
      float p0 = tau1*(a[2][2] + a[3][2]*x1);
      float p1 = tau1*(a[3][2] + a[3][3]*x1);
      float al = -0.5f*tau1*(p0 + p1*x1);
      p0 += al; p1 += al*x1;
      a[2][2] -= 2.0f*p0;
      a[3][2] -= x1*p0 + p1;
      a[3][3] -= 2.0f*x1*p1;
    }
    v42 = x1;
  }
  e[2] = a[3][2];
  d[0]=a[0][0]; d[1]=a[1][1]; d[2]=a[2][2]; d[3]=a[3][3];
  float z[4][4] = {{1,0,0,0},{0,1,0,0},{0,0,1,0},{0,0,0,1}};
  const float eps = F32_EPS;
  const float eps2 = F32_EPS2;
  const float safmin = F32_SAFMIN;
  int jtot = 0;
  const int nmaxit = 120;
  int l1 = 0;
  bool fail = false;
  while (!fail){
    if (l1 > 3) break;
    if (l1 > 0) e[l1-1] = 0.0f;
    int lend = 3;
    for (int mm = l1; mm <= 2; ++mm){
      float tst = fabsf(e[mm]);
      if (tst == 0.0f){ lend = mm; break; }
      if (tst <= (sqrtf(fabsf(d[mm]))*sqrtf(fabsf(d[mm+1])))*eps){ e[mm] = 0.0f; lend = mm; break; }
    }
    int l = l1;
    int lsv = l, lendsv = lend;
    l1 = lend + 1;
    if (lend == l) continue;
    float anorm = fabsf(d[l]);
    for (int ii=l+1; ii<=lend; ++ii) anorm = fmaxf(anorm, fabsf(d[ii]));
    for (int ii=l; ii<lend; ++ii)    anorm = fmaxf(anorm, fabsf(e[ii]));
    if (anorm == 0.0f) continue;
    if (fabsf(d[lend]) < fabsf(d[l])){ lend = lsv; l = lendsv; }
    if (lend > l){
      for (;;){
        int m = lend;
        if (l != lend){
          for (int mm=l; mm<=lend-1; ++mm){
            float tst = e[mm]*e[mm];
            if (tst <= (eps2*fabsf(d[mm]))*fabsf(d[mm+1]) + safmin){ m = mm; break; }
          }
        }
        if (m < lend) e[m] = 0.0f;
        float p = d[l];
        if (m == l){
          d[l] = p; ++l;
          if (l <= lend) continue;
          break;
        }
        if (m == l+1){
          float rt1, rt2, c, s;
          slaev2(d[l], e[l], d[l+1], rt1, rt2, c, s);
          #pragma unroll
          for (int r2=0;r2<4;r2++){
            float t_ = z[r2][l+1];
            z[r2][l+1] = c*t_ - s*z[r2][l];
            z[r2][l]   = s*t_ + c*z[r2][l];
          }
          d[l]=rt1; d[l+1]=rt2; e[l]=0.0f;
          l += 2;
          if (l <= lend) continue;
          break;
        }
        if (jtot == nmaxit){ fail = true; break; }
        ++jtot;
        float g = (d[l+1]-p)/(2.0f*e[l]);
        float r_ = slapy2(g, 1.0f);
        g = d[m] - p + e[l]/(g + s_sign(r_, g));
        float s = 1.0f, c = 1.0f;
        p = 0.0f;
        float csv[3], snv[3];
        for (int i=m-1; i>=l; --i){
          float f = s*e[i], b = c*e[i];
          slartg(g, f, c, s, r_);
          if (i != m-1) e[i+1] = r_;
          g = d[i+1] - p;
          r_ = (d[i]-g)*s + 2.0f*c*b;
          p = s*r_;
          d[i+1] = g + p;
          g = c*r_ - b;
          csv[i] = c; snv[i] = -s;
        }
        for (int i=m-1; i>=l; --i){
          float cc = csv[i], ss = snv[i];
          #pragma unroll
          for (int r2=0;r2<4;r2++){
            float t_ = z[r2][i+1];
            z[r2][i+1] = cc*t_ - ss*z[r2][i];
            z[r2][i]   = ss*t_ + cc*z[r2][i];
          }
        }
        d[l] -= p; e[l] = g;
      }
    } else {
      for (;;){
        int m = lend;
        if (l != lend){
          for (int mm=l; mm>=lend+1; --mm){
            float tst = e[mm-1]*e[mm-1];
            if (tst <= (eps2*fabsf(d[mm]))*fabsf(d[mm-1]) + safmin){ m = mm; break; }
          }
        }
        if (m > lend) e[m-1] = 0.0f;
        float p = d[l];
        if (m == l){
          d[l] = p; --l;
          if (l >= lend) continue;
          break;
        }
        if (m == l-1){
          float rt1, rt2, c, s;
          slaev2(d[l-1], e[l-1], d[l], rt1, rt2, c, s);
          #pragma unroll
          for (int r2=0;r2<4;r2++){
            float t_ = z[r2][l];
            z[r2][l]   = c*t_ - s*z[r2][l-1];
            z[r2][l-1] = s*t_ + c*z[r2][l-1];
          }
          d[l-1]=rt1; d[l]=rt2; e[l-1]=0.0f;
          l -= 2;
          if (l >= lend) continue;
          break;
        }
        if (jtot == nmaxit){ fail = true; break; }
        ++jtot;
        float g = (d[l-1]-p)/(2.0f*e[l-1]);
        float r_ = slapy2(g, 1.0f);
        g = d[m] - p + e[l-1]/(g + s_sign(r_, g));
        float s = 1.0f, c = 1.0f;
        p = 0.0f;
        float csv[3], snv[3];
        for (int i=m; i<=l-1; ++i){
          float f = s*e[i], b = c*e[i];
          slartg(g, f, c, s, r_);
          if (i != m) e[i-1] = r_;
          g = d[i] - p;
          r_ = (d[i+1]-g)*s + 2.0f*c*b;
          p = s*r_;
          d[i] = g + p;
          g = c*r_ - b;
          csv[i] = c; snv[i] = s;
        }
        for (int i=m; i<=l-1; ++i){
          float cc = csv[i], ss = snv[i];
          #pragma unroll
          for (int r2=0;r2<4;r2++){
            float t_ = z[r2][i+1];
            z[r2][i+1] = cc*t_ - ss*z[r2][i];
            z[r2][i]   = ss*t_ + cc*z[r2][i];
          }
        }
        d[l] -= p; e[l-1] = g;
      }
    }
  }
  for (int ii=1; ii<4; ++ii){
    int i0 = ii-1, k0 = i0;
    float p = d[i0];
    for (int j2=ii; j2<4; ++j2) if (d[j2] < p){ k0 = j2; p = d[j2]; }
    if (k0 != i0){
      d[k0] = d[i0]; d[i0] = p;
      #pragma unroll
      for (int r2=0;r2<4;r2++){ float t_ = z[r2][i0]; z[r2][i0] = z[r2][k0]; z[r2][k0] = t_; }
    }
  }
  float w0 = z[0][3], w1 = z[1][3], w2 = z[2][3], w3 = z[3][3];
  if (tau1 != 0.0f){
    float dv = w2 + v42*w3;
    w2 -= tau1*dv;
    w3 -= tau1*dv*v42;
  }
  if (tau0 != 0.0f){
    float dv = w1 + v31*w2 + v41*w3;
    w1 -= tau0*dv;
    w2 -= tau0*dv*v31;
    w3 -= tau0*dv*v41;
  }
  q[0]=w0; q[1]=w1; q[2]=w2; q[3]=w3;
}

// ---------------- kernels ----------------
__global__ void fill_kernel(float* __restrict__ p, int nelem, float val){
  int i = blockIdx.x*blockDim.x + threadIdx.x;
  if (i < nelem) p[i] = val;
}

__global__ void rigid_kernel(const float* __restrict__ bb, float* __restrict__ Rg, float* __restrict__ tg){
  int n = blockIdx.x*blockDim.x + threadIdx.x;
  if (n >= NN) return;
  const float* p = bb + (size_t)n*9;
  float nx=p[0],ny=p[1],nz=p[2], cax=p[3],cay=p[4],caz=p[5], cx=p[6],cy=p[7],cz=p[8];
  float e1x=cx-cax, e1y=cy-cay, e1z=cz-caz;
  float n1 = sqrtf(e1x*e1x+e1y*e1y+e1z*e1z);
  e1x/=n1; e1y/=n1; e1z/=n1;
  float ux=nx-cax, uy=ny-cay, uz=nz-caz;
  float du = ux*e1x+uy*e1y+uz*e1z;
  float e2x=ux-du*e1x, e2y=uy-du*e1y, e2z=uz-du*e1z;
  float n2 = sqrtf(e2x*e2x+e2y*e2y+e2z*e2z);
  e2x/=n2; e2y/=n2; e2z/=n2;
  float e3x=e1y*e2z-e1z*e2y, e3y=e1z*e2x-e1x*e2z, e3z=e1x*e2y-e1y*e2x;
  float* R = Rg + (size_t)n*9;
  R[0]=e1x; R[1]=e2x; R[2]=e3x;
  R[3]=e1y; R[4]=e2y; R[5]=e3y;
  R[6]=e1z; R[7]=e2z; R[8]=e3z;
  tg[(size_t)n*3+0]=cax; tg[(size_t)n*3+1]=cay; tg[(size_t)n*3+2]=caz;
}

__global__ __launch_bounds__(256) void ln_kernel(const float* __restrict__ x,
    const float* __restrict__ g, const float* __restrict__ b, float* __restrict__ xln){
  int n = blockIdx.x, t = threadIdx.x;
  __shared__ float rbuf[256];
  float v[5];
  float s = 0.0f;
  #pragma unroll
  for (int i=0;i<5;i++){ v[i] = x[(size_t)n*IND + t + i*256]; s += v[i]; }
  float mu = bsumf(s, rbuf)*(1.0f/IND);
  float pv = 0.0f;
  #pragma unroll
  for (int i=0;i<5;i++){ float dd = v[i]-mu; pv += dd*dd; }
  float var = bsumf(pv, rbuf)*(1.0f/IND);
  float rs = 1.0f/sqrtf(var + 1e-5f);
  #pragma unroll
  for (int i=0;i<5;i++){
    int k = t + i*256;
    xln[(size_t)n*IND + k] = g[k]*((v[i]-mu)*rs) + b[k];
  }
}

__global__ __launch_bounds__(256) void emb0_kernel(const float* __restrict__ xln,
    const float* __restrict__ W, const float* __restrict__ bias, float* __restrict__ emb){
  int n0 = blockIdx.x*8, j = threadIdx.x;
  float acc[8];
  #pragma unroll
  for (int i=0;i<8;i++) acc[i] = bias[j];
  for (int k=0;k<IND;k+=4){
    float w0=W[(size_t)(k+0)*EMB+j], w1=W[(size_t)(k+1)*EMB+j], w2=W[(size_t)(k+2)*EMB+j], w3=W[(size_t)(k+3)*EMB+j];
    #pragma unroll
    for (int i=0;i<8;i++){
      const float* xp = xln + (size_t)(n0+i)*IND + k;
      acc[i] += xp[0]*w0 + xp[1]*w1 + xp[2]*w2 + xp[3]*w3;
    }
  }
  #pragma unroll
  for (int i=0;i<8;i++) emb[(size_t)(n0+i)*EMB + j] = acc[i];
}

__global__ __launch_bounds__(64) void edge_kernel(const float* __restrict__ bb,
    const float* __restrict__ Rg, const float* __restrict__ tg,
    const int* __restrict__ col, float* __restrict__ Redge, float* __restrict__ eattr){
  int e = blockIdx.x*64 + threadIdx.x;
  if (e >= EE) return;
  int i = e/KK;
  int jn = col[e];
  float Ri[9], Rj[9];
  #pragma unroll
  for (int a=0;a<9;a++){ Ri[a]=Rg[(size_t)i*9+a]; Rj[a]=Rg[(size_t)jn*9+a]; }
  float dt0 = tg[(size_t)jn*3+0]-tg[(size_t)i*3+0];
  float dt1 = tg[(size_t)jn*3+1]-tg[(size_t)i*3+1];
  float dt2 = tg[(size_t)jn*3+2]-tg[(size_t)i*3+2];
  float Re[9];
  #pragma unroll
  for (int a=0;a<3;a++){
    #pragma unroll
    for (int c=0;c<3;c++)
      Re[a*3+c] = Ri[0+a]*Rj[0+c] + Ri[3+a]*Rj[3+c] + Ri[6+a]*Rj[6+c];
  }
  float te0 = Ri[0]*dt0 + Ri[3]*dt1 + Ri[6]*dt2;
  float te1 = Ri[1]*dt0 + Ri[4]*dt1 + Ri[7]*dt2;
  float te2 = Ri[2]*dt0 + Ri[5]*dt1 + Ri[8]*dt2;
  float xx=Re[0], xy=Re[1], xz=Re[2], yx=Re[3], yy=Re[4], yz=Re[5], zx=Re[6], zy=Re[7], zz=Re[8];
  float km[4][4];
  km[0][0]=(xx+yy+zz)/3.0f; km[0][1]=(zy-yz)/3.0f;    km[0][2]=(xz-zx)/3.0f;    km[0][3]=(yx-xy)/3.0f;
  km[1][0]=km[0][1];        km[1][1]=(xx-yy-zz)/3.0f; km[1][2]=(xy+yx)/3.0f;    km[1][3]=(xz+zx)/3.0f;
  km[2][0]=km[0][2];        km[2][1]=km[1][2];        km[2][2]=(yy-xx-zz)/3.0f; km[2][3]=(yz+zy)/3.0f;
  km[3][0]=km[0][3];        km[3][1]=km[1][3];        km[3][2]=km[2][3];        km[3][3]=(zz-xx-yy)/3.0f;
  float q[4];
  sym4_quat_f32(km, q);
  float* ea = eattr + (size_t)e*EAP;
  ea[0]=q[0]; ea[1]=q[1]; ea[2]=q[2]; ea[3]=q[3];
  ea[4]=te0;  ea[5]=te1;  ea[6]=te2;
  int cd = i - jn; if (cd < 0) cd = -cd;
  ea[7] = logf((float)cd + 1.0f);
  ea[8] = logf(sqrtf(te0*te0+te1*te1+te2*te2) + 1e-8f);
  const float* bi = bb + (size_t)i*9;
  const float* bj = bb + (size_t)jn*9;
  int idx = 9;
  #pragma unroll
  for (int a=0;a<3;a++){
    float ax=bi[a*3+0], ay=bi[a*3+1], az=bi[a*3+2];
    #pragma unroll
    for (int b2=0;b2<3;b2++){
      float dx=ax-bj[b2*3+0], dy=ay-bj[b2*3+1], dz=az-bj[b2*3+2];
      float dd = sqrtf(fmaxf(dx*dx+dy*dy+dz*dz, 1e-12f));
      #pragma unroll
      for (int kb=0;kb<16;kb++){
        float muv = 1.3333334f*(float)kb;
        float df = dd - muv;
        ea[idx] = expf(-0.5f*df*df);
        idx++;
      }
    }
  }
  ea[153]=0.0f; ea[154]=0.0f; ea[155]=0.0f;   // zero pad
  #pragma unroll
  for (int a=0;a<9;a++) Redge[(size_t)e*9+a] = Re[a];
}

__global__ void vjr_kernel(const float* __restrict__ Redge, const float* __restrict__ v_in,
    const int* __restrict__ col, float* __restrict__ vjrg){
  int idx = blockIdx.x*blockDim.x + threadIdx.x;
  if (idx >= EE*V3) return;
  int e = idx/V3, r = idx - e*V3;
  int m = r/3, ii = r - m*3;
  int cj = col[e];
  const float* Rp = Redge + (size_t)e*9;
  const float* vp = v_in + (size_t)cj*V3 + m*3;
  vjrg[(size_t)e*16 + r] = Rp[ii*3+0]*vp[0] + Rp[ii*3+1]*vp[1] + Rp[ii*3+2]*vp[2];
}

// h1 with LDS staging of all block-uniform operands (arithmetic bit-identical to R7).
__global__ __launch_bounds__(256) void h1_kernel(
    const float* __restrict__ emb_in, const float* __restrict__ v_in,
    const float* __restrict__ vjrg, const float* __restrict__ eattr,
    const int* __restrict__ col,
    const float* __restrict__ W1, const float* __restrict__ b1,
    float* __restrict__ h1g){
  int n = blockIdx.x, j = threadIdx.x;
  size_t e0 = (size_t)n*KK;
  __shared__ float s_emb[KK][EMB];   // 30 KB  gathered x_j rows
  __shared__ float s_ea [KK][EAP];   // 18.7 KB edge attrs
  __shared__ float s_vjr[KK][16];    // 1.9 KB
  __shared__ float s_xi [EMB];       // 1 KB
  __shared__ float s_vi [V3];
  // coalesced staging
  #pragma unroll
  for (int e=0;e<KK;e++){
    int cj = col[e0+e];
    s_emb[e][j] = emb_in[(size_t)cj*EMB + j];
  }
  s_xi[j] = emb_in[(size_t)n*EMB + j];
  if (j < V3) s_vi[j] = v_in[(size_t)n*V3 + j];
  for (int idx=j; idx<KK*EAP; idx+=256){
    int e = idx/EAP, kk = idx - e*EAP;
    s_ea[e][kk] = eattr[(e0+e)*EAP + kk];
  }
  for (int idx=j; idx<KK*16; idx+=256){
    int e = idx>>4, r = idx&15;
    s_vjr[e][r] = vjrg[(e0+e)*16 + r];
  }
  __syncthreads();

  float csh = b1[j];
  {
    for (int k=0;k<EMB;k+=4){
      float w0=W1[(size_t)(k+0)*EMB+j], w1=W1[(size_t)(k+1)*EMB+j], w2=W1[(size_t)(k+2)*EMB+j], w3=W1[(size_t)(k+3)*EMB+j];
      csh += s_xi[k+0]*w0 + s_xi[k+1]*w1 + s_xi[k+2]*w2 + s_xi[k+3]*w3;
    }
    #pragma unroll
    for (int r=0;r<V3;r++) csh += s_vi[r]*(W1[(size_t)(512+r)*EMB+j] + W1[(size_t)(542+r)*EMB+j]);
  }
  float acc[KK];
  #pragma unroll
  for (int e=0;e<KK;e++) acc[e] = csh;
  // x_j part: W1 rows 256..511
  #pragma unroll
  for (int eg=0; eg<KK; eg+=15){
    for (int k=0;k<EMB;k+=4){
      float w0=W1[(size_t)(256+k)*EMB+j], w1=W1[(size_t)(257+k)*EMB+j], w2=W1[(size_t)(258+k)*EMB+j], w3=W1[(size_t)(259+k)*EMB+j];
      #pragma unroll
      for (int qq=0;qq<15;qq++){
        const float* xp = &s_emb[eg+qq][k];
        acc[eg+qq] += xp[0]*w0 + xp[1]*w1 + xp[2]*w2 + xp[3]*w3;
      }
    }
  }
  // vj_rot part: rows 527..541 minus 542..556
  {
    float wv[V3];
    #pragma unroll
    for (int r=0;r<V3;r++) wv[r] = W1[(size_t)(527+r)*EMB+j] - W1[(size_t)(542+r)*EMB+j];
    #pragma unroll
    for (int e=0;e<KK;e++){
      float a = acc[e];
      #pragma unroll
      for (int r=0;r<V3;r++) a += s_vjr[e][r]*wv[r];
      acc[e] = a;
    }
  }
  // edge-attr part: rows 557..709
  #pragma unroll
  for (int eg=0; eg<KK; eg+=15){
    for (int k=0;k<152;k+=4){
      float w0=W1[(size_t)(557+k)*EMB+j], w1=W1[(size_t)(558+k)*EMB+j], w2=W1[(size_t)(559+k)*EMB+j], w3=W1[(size_t)(560+k)*EMB+j];
      #pragma unroll
      for (int qq=0;qq<15;qq++){
        const float* ap = &s_ea[eg+qq][k];
        acc[eg+qq] += ap[0]*w0 + ap[1]*w1 + ap[2]*w2 + ap[3]*w3;
      }
    }
    float wl = W1[(size_t)709*EMB+j];
    #pragma unroll
    for (int qq=0;qq<15;qq++) acc[eg+qq] += s_ea[eg+qq][152]*wl;
  }
  #pragma unroll
  for (int e=0;e<KK;e++) h1g[(e0+e)*EMB + j] = gelu_f(acc[e]);
}

__global__ __launch_bounds__(256) void h2_kernel(
    const float* __restrict__ emb_in,
    const float* __restrict__ h1g,
    const float* __restrict__ W2, const float* __restrict__ b2,
    const float* __restrict__ W3, const float* __restrict__ b3,
    const float* __restrict__ lng, const float* __restrict__ lnb,
    float* __restrict__ emb_out){
  int n = blockIdx.x, j = threadIdx.x;
  __shared__ float s_h1[KK][EMB];    // 30 KB
  __shared__ float sbuf[EMB];
  __shared__ float rbuf[256];
  size_t e0 = (size_t)n*KK;
  #pragma unroll
  for (int e=0;e<KK;e++) s_h1[e][j] = h1g[(e0+e)*EMB + j];
  __syncthreads();
  float acc[KK];
  #pragma unroll
  for (int e=0;e<KK;e++) acc[e] = b2[j];
  #pragma unroll
  for (int eg=0; eg<KK; eg+=15){
    for (int k=0;k<EMB;k+=4){
      float w0=W2[(size_t)(k+0)*EMB+j], w1=W2[(size_t)(k+1)*EMB+j], w2=W2[(size_t)(k+2)*EMB+j], w3=W2[(size_t)(k+3)*EMB+j];
      #pragma unroll
      for (int qq=0;qq<15;qq++){
        const float* hp = &s_h1[eg+qq][k];
        acc[eg+qq] += hp[0]*w0 + hp[1]*w1 + hp[2]*w2 + hp[3]*w3;
      }
    }
  }
  float s = 0.0f;
  #pragma unroll
  for (int e=0;e<KK;e++) s += gelu_f(acc[e]);
  sbuf[j] = s;
  __syncthreads();
  float ag = 0.0f;
  for (int k=0;k<EMB;k+=4){
    float4 s4 = *(const float4*)&sbuf[k];
    ag += s4.x*W3[(size_t)(k+0)*EMB+j] + s4.y*W3[(size_t)(k+1)*EMB+j]
        + s4.z*W3[(size_t)(k+2)*EMB+j] + s4.w*W3[(size_t)(k+3)*EMB+j];
  }
  ag = ag*(1.0f/30.0f) + b3[j];
  float u = emb_in[(size_t)n*EMB+j] + ag;
  float mu = bsumf(u, rbuf)*(1.0f/EMB);
  float dl = u - mu;
  float var = bsumf(dl*dl, rbuf)*(1.0f/EMB);
  float rs = 1.0f/sqrtf(var + 1e-5f);
  float y = lng[j]*dl*rs + lnb[j];
  emb_out[(size_t)n*EMB+j] = y;
}

// Fused vu + f32 sgeqr2/sorg2r per graph — IDENTICAL arithmetic to R7 (probes removed).
__global__ __launch_bounds__(256) void vu_qr_kernel(
    const float* __restrict__ emb_new, const float* __restrict__ v_in,
    const float* __restrict__ vW, float* __restrict__ vout){
  int g = blockIdx.x, t = threadIdx.x;
  __shared__ float A[QRM*QRN];
  __shared__ float meanv[V3];
  __shared__ float taus[QRN];
  __shared__ float sh[2];
  int n = g*LSZ + t;
  const float* em = emb_new + (size_t)n*EMB;
  const float* vi = v_in + (size_t)n*V3;
  float a[V3];
  #pragma unroll
  for (int j=0;j<V3;j++) a[j] = vi[j];
  for (int k=0;k<EMB;k++){
    float e = em[k];
    #pragma unroll
    for (int j=0;j<V3;j++) a[j] += e*vW[k*V3+j];
  }
  #pragma unroll
  for (int r=0;r<V3;r++){
    float vv = vi[r];
    #pragma unroll
    for (int j=0;j<V3;j++) a[j] += vv*vW[(EMB+r)*V3+j];
  }
  #pragma unroll
  for (int j=0;j<V3;j++) A[t*V3+j] = a[j];
  __syncthreads();
  if (t < V3){
    float s = 0.0f;
    for (int l0=0;l0<LSZ;l0++) s += A[l0*V3+t];
    meanv[t] = s/(float)LSZ;
  }
  __syncthreads();
  #pragma unroll
  for (int j=0;j<V3;j++) A[t*V3+j] -= meanv[j];
  __syncthreads();
  // ---- sgeqr2 ----
  for (int i=0;i<QRN;i++){
    if (t == 0){
      float s0=0,s1=0,s2=0,s3=0;
      int r=i+1;
      for (; r+3<QRM; r+=4){
        float x0=A[r*QRN+i], x1=A[(r+1)*QRN+i], x2=A[(r+2)*QRN+i], x3=A[(r+3)*QRN+i];
        s0+=x0*x0; s1+=x1*x1; s2+=x2*x2; s3+=x3*x3;
      }
      for (; r<QRM; r++){ float x=A[r*QRN+i]; s0+=x*x; }
      float xn2 = (s0+s1)+(s2+s3);
      float alpha = A[i*QRN+i];
      float taui = 0.0f, sc = 1.0f;
      if (xn2 != 0.0f){
        float beta = -s_sign(slapy2(alpha, sqrtf(xn2)), alpha);
        taui = (beta - alpha)/beta;
        sc = 1.0f/(alpha - beta);
      }
      taus[i] = taui; sh[0] = sc;
    }
    __syncthreads();
    {
      float sc = sh[0];
      for (int r=i+1+t; r<QRM; r+=256) A[r*QRN+i] *= sc;
    }
    __syncthreads();
    for (int j=i+1;j<QRN;j++){
      if (t == 0){
        float s0=A[i*QRN+j], s1=0,s2=0,s3=0;
        int r=i+1;
        for (; r+3<QRM; r+=4){
          s0 += A[r*QRN+i]*A[r*QRN+j];
          s1 += A[(r+1)*QRN+i]*A[(r+1)*QRN+j];
          s2 += A[(r+2)*QRN+i]*A[(r+2)*QRN+j];
          s3 += A[(r+3)*QRN+i]*A[(r+3)*QRN+j];
        }
        for (; r<QRM; r++) s0 += A[r*QRN+i]*A[r*QRN+j];
        sh[0] = taus[i]*((s0+s1)+(s2+s3));
      }
      __syncthreads();
      {
        float w = sh[0];
        for (int r=i+t; r<QRM; r+=256){
          float vr = (r==i) ? 1.0f : A[r*QRN+i];
          A[r*QRN+j] -= w*vr;
        }
      }
      __syncthreads();
    }
  }
  // ---- sorg2r ----
  for (int i=QRN-1;i>=0;i--){
    for (int j=i+1;j<QRN;j++){
      if (t == 0){
        float s0=A[i*QRN+j], s1=0,s2=0,s3=0;
        int r=i+1;
        for (; r+3<QRM; r+=4){
          s0 += A[r*QRN+i]*A[r*QRN+j];
          s1 += A[(r+1)*QRN+i]*A[(r+1)*QRN+j];
          s2 += A[(r+2)*QRN+i]*A[(r+2)*QRN+j];
          s3 += A[(r+3)*QRN+i]*A[(r+3)*QRN+j];
        }
        for (; r<QRM; r++) s0 += A[r*QRN+i]*A[r*QRN+j];
        sh[0] = taus[i]*((s0+s1)+(s2+s3));
      }
      __syncthreads();
      {
        float w = sh[0];
        for (int r=i+t; r<QRM; r+=256){
          float vr = (r==i) ? 1.0f : A[r*QRN+i];
          A[r*QRN+j] -= w*vr;
        }
      }
      __syncthreads();
    }
    {
      float taui = taus[i];
      for (int r=i+1+t; r<QRM; r+=256) A[r*QRN+i] *= -taui;
    }
    __syncthreads();
    if (t == 0) A[i*QRN+i] = 1.0f - taus[i];
    if (t < i) A[t*QRN+i] = 0.0f;
    __syncthreads();
  }
  for (int idx=t; idx<QRM*QRN; idx+=256)
    vout[(size_t)g*LSZ*V3 + idx] = 16.0f*A[idx];
}

__global__ __launch_bounds__(256) void final_kernel(const float* __restrict__ embf,
    const float* __restrict__ vf, const float* __restrict__ Rg, float* __restrict__ out){
  int n = blockIdx.x, t = threadIdx.x;
  out[(size_t)n*EMB + t] = embf[(size_t)n*EMB + t];
  if (t < V3){
    int m = t/3, ii = t - m*3;
    const float* Rp = Rg + (size_t)n*9;
    const float* vp = vf + (size_t)n*V3 + m*3;
    float val = Rp[ii*3+0]*vp[0] + Rp[ii*3+1]*vp[1] + Rp[ii*3+2]*vp[2];
    out[(size_t)NN*EMB + (size_t)n*V3 + t] = val;
  }
}

// ---------------- host ----------------
extern "C" void kernel_launch(void* const* d_in, const int* in_sizes, int n_in,
                              void* d_out, int out_size, void* d_ws, size_t ws_size,
                              hipStream_t stream){
  (void)in_sizes; (void)n_in; (void)out_size; (void)ws_size;
  const float* x       = (const float*)d_in[0];
  const float* bb      = (const float*)d_in[1];
  const float* in_ln_g = (const float*)d_in[2];
  const float* in_ln_b = (const float*)d_in[3];
  const float* in_W    = (const float*)d_in[4];
  const float* in_b    = (const float*)d_in[5];
  const float* msg_W1  = (const float*)d_in[6];
  const float* msg_b1  = (const float*)d_in[7];
  const float* msg_W2  = (const float*)d_in[8];
  const float* msg_b2  = (const float*)d_in[9];
  const float* msg_W3  = (const float*)d_in[10];
  const float* msg_b3  = (const float*)d_in[11];
  const float* vect_W  = (const float*)d_in[12];
  const float* ln_g    = (const float*)d_in[13];
  const float* ln_b    = (const float*)d_in[14];
  const int*   col     = (const int*)d_in[16];

  char* p = (char*)d_ws;
  auto alloc = [&](size_t bytes)->void*{ void* r = (void*)p; p += (bytes + 255) & ~(size_t)255; return r; };
  float*  Rg    = (float*) alloc((size_t)NN*9*4);
  float*  tg    = (float*) alloc((size_t)NN*3*4);
  float*  xln   = (float*) alloc((size_t)NN*IND*4);
  float*  eA    = (float*) alloc((size_t)NN*EMB*4);
  float*  eB    = (float*) alloc((size_t)NN*EMB*4);
  float*  vA    = (float*) alloc((size_t)NN*V3*4);
  float*  vB    = (float*) alloc((size_t)NN*V3*4);
  float*  Redge = (float*) alloc((size_t)EE*9*4);
  float*  eattr = (float*) alloc((size_t)EE*EAP*4);
  float*  vjrg  = (float*) alloc((size_t)EE*16*4);
  float*  h1g   = (float*) alloc((size_t)EE*EMB*4);

  const int NV = NN*V3;
  fill_kernel<<<(NV+255)/256, 256, 0, stream>>>(vA, NV, 0.0f);
  rigid_kernel<<<(NN+63)/64, 64, 0, stream>>>(bb, Rg, tg);
  ln_kernel<<<NN, 256, 0, stream>>>(x, in_ln_g, in_ln_b, xln);
  emb0_kernel<<<NN/8, 256, 0, stream>>>(xln, in_W, in_b, eA);
  edge_kernel<<<(EE+63)/64, 64, 0, stream>>>(bb, Rg, tg, col, Redge, eattr);

  float* ein = eA; float* eout = eB; float* vin = vA; float* vout = vB;
  for (int l=0; l<3; ++l){
    vjr_kernel<<<(EE*V3+255)/256, 256, 0, stream>>>(Redge, vin, col, vjrg);
    h1_kernel<<<NN, 256, 0, stream>>>(ein, vin, vjrg, eattr, col,
        msg_W1 + (size_t)l*710*EMB, msg_b1 + (size_t)l*EMB, h1g);
    h2_kernel<<<NN, 256, 0, stream>>>(ein, h1g,
        msg_W2 + (size_t)l*EMB*EMB, msg_b2 + (size_t)l*EMB,
        msg_W3 + (size_t)l*EMB*EMB, msg_b3 + (size_t)l*EMB,
        ln_g + (size_t)l*EMB, ln_b + (size_t)l*EMB, eout);
    vu_qr_kernel<<<NG, 256, 0, stream>>>(eout, vin,
        vect_W + (size_t)l*(EMB+V3)*V3, vout);
    float* tmp = ein; ein = eout; eout = tmp;
    tmp = vin; vin = vout; vout = tmp;
  }
  final_kernel<<<NN, 256, 0, stream>>>(ein, vin, Rg, (float*)d_out);
}

// Round 9
// 2561.635 us; speedup vs baseline: 1.4475x; 1.0051x over previous
//
#include <hip/hip_runtime.h>
#include <hip/hip_bf16.h>

#define NG   8
#define LSZ  256
#define NN   2048
#define KK   30
#define EE   61440
#define IND  1280
#define EMB  256
#define V3   15
#define EAP  156
#define QRM  768
#define QRN  5

#define F32_EPS    5.9604645e-08f
#define F32_EPS2   3.5527137e-15f
#define F32_SAFMIN 1.17549435e-38f

__device__ __forceinline__ float bsumf(float v, float* rbuf){
  int t = threadIdx.x;
  __syncthreads();
  rbuf[t] = v;
  __syncthreads();
  for (int s=128; s>0; s>>=1){
    if (t < s) rbuf[t] += rbuf[t+s];
    __syncthreads();
  }
  float r = rbuf[0];
  __syncthreads();
  return r;
}
__device__ __forceinline__ float gelu_f(float x){
  return 0.5f*x*(1.0f + erff(x*0.70710678f));
}
__device__ __forceinline__ float s_sign(float a, float b){ return (b >= 0.0f) ? fabsf(a) : -fabsf(a); }
__device__ __forceinline__ float slapy2(float x, float y){
  float xa = fabsf(x), ya = fabsf(y);
  float w = fmaxf(xa, ya), z = fminf(xa, ya);
  if (z == 0.0f) return w;
  float t = z/w;
  return w*sqrtf(1.0f + t*t);
}
// LAPACK >=3.10 slartg (f32)
__device__ void slartg(float f, float g, float& c, float& s, float& r){
  const float safmin = F32_SAFMIN;
  const float safmax = 8.5070592e+37f;
  const float rtmin  = 1.0842022e-19f;
  const float rtmax  = 6.5243586e+18f;
  float f1 = fabsf(f), g1 = fabsf(g);
  if (g == 0.0f){ c = 1.0f; s = 0.0f; r = f; }
  else if (f == 0.0f){ c = 0.0f; s = (g >= 0.0f ? 1.0f : -1.0f); r = g1; }
  else {
    if (f1 > rtmin && f1 < rtmax && g1 > rtmin && g1 < rtmax){
      float d = sqrtf(f*f + g*g);
      c = f1/d;
      r = (f >= 0.0f ? d : -d);
      s = g/r;
    } else {
      float u = fminf(safmax, fmaxf(safmin, fmaxf(f1,g1)));
      float fs = f/u, gs = g/u;
      float d = sqrtf(fs*fs + gs*gs);
      c = fabsf(fs)/d;
      r = (f >= 0.0f ? d : -d);
      s = gs/r;
      r = r*u;
    }
  }
}
__device__ void slaev2(float a, float b, float c, float& rt1, float& rt2, float& cs1, float& sn1){
  float sm = a + c, df = a - c, adf = fabsf(df), tb = b + b, ab = fabsf(tb);
  float acmx, acmn;
  if (fabsf(a) > fabsf(c)) { acmx=a; acmn=c; } else { acmx=c; acmn=a; }
  float rt;
  if (adf > ab){ float t = ab/adf; rt = adf*sqrtf(1.0f+t*t); }
  else if (adf < ab){ float t = adf/ab; rt = ab*sqrtf(1.0f+t*t); }
  else rt = ab*sqrtf(2.0f);
  int sgn1;
  if (sm < 0.0f){ rt1 = 0.5f*(sm-rt); sgn1 = -1; rt2 = (acmx/rt1)*acmn - (b/rt1)*b; }
  else if (sm > 0.0f){ rt1 = 0.5f*(sm+rt); sgn1 = 1; rt2 = (acmx/rt1)*acmn - (b/rt1)*b; }
  else { rt1 = 0.5f*rt; rt2 = -0.5f*rt; sgn1 = 1; }
  float cs; int sgn2;
  if (df >= 0.0f){ cs = df + rt; sgn2 = 1; } else { cs = df - rt; sgn2 = -1; }
  float acs = fabsf(cs);
  if (acs > ab){
    float ct = -tb/cs; sn1 = 1.0f/sqrtf(1.0f+ct*ct); cs1 = ct*sn1;
  } else {
    if (ab == 0.0f){ cs1 = 1.0f; sn1 = 0.0f; }
    else { float tn = -cs/tb; cs1 = 1.0f/sqrtf(1.0f+tn*tn); sn1 = tn*cs1; }
  }
  if (sgn1 == sgn2){ float tn = cs1; cs1 = -sn1; sn1 = tn; }
}

// f32 ssytd2('L') + ssteqr('I') for 4x4; returns eigvec of largest eigenvalue.
__device__ void sym4_quat_f32(float (&a)[4][4], float* q){
  float d[4], e[3];
  float tau0 = 0.0f, tau1 = 0.0f;
  float v31 = 0.0f, v41 = 0.0f, v42 = 0.0f;
  {
    float alpha = a[1][0];
    float x1 = a[2][0], x2 = a[3][0];
    float xnorm = sqrtf(x1*x1 + x2*x2);
    if (xnorm == 0.0f){ tau0 = 0.0f; e[0] = alpha; }
    else {
      float beta = -s_sign(slapy2(alpha, xnorm), alpha);
      tau0 = (beta - alpha)/beta;
      float sc = 1.0f/(alpha - beta);
      x1 *= sc; x2 *= sc;
      e[0] = beta;
      float p0 = tau0*(a[1][1] + a[2][1]*x1 + a[3][1]*x2);
      float p1 = tau0*(a[2][1] + a[2][2]*x1 + a[3][2]*x2);
      float p2 = tau0*(a[3][1] + a[3][2]*x1 + a[3][3]*x2);
      float al = -0.5f*tau0*(p0 + p1*x1 + p2*x2);
      p0 += al; p1 += al*x1; p2 += al*x2;
      a[1][1] -= 2.0f*p0;
      a[2][1] -= x1*p0 + p1;
      a[3][1] -= x2*p0 + p2;
      a[2][2] -= 2.0f*x1*p1;
      a[3][2] -= x2*p1 + p2*x1;
      a[3][3] -= 2.0f*x2*p2;
    }
    v31 = x1; v41 = x2;
  }
  {
    float alpha = a[2][1];
    float x1 = a[3][1];
    float xnorm = fabsf(x1);
    if (xnorm == 0.0f){ tau1 = 0.0f; e[1] = alpha; }
    else {
      float beta = -s_sign(slapy2(alpha, xnorm), alpha);
      tau1 = (beta - alpha)/beta;
      x1 *= 1.0f/(alpha - beta);
      e[1] = beta;
      float p0 = tau1*(a[2][2] + a[3][2]*x1);
      float p1 = tau1*(a[3][2] + a[3][3]*x1);
      float al = -0.5f*tau1*(p0 + p1*x1);
      p0 += al; p1 += al*x1;
      a[2][2] -= 2.0f*p0;
      a[3][2] -= x1*p0 + p1;
      a[3][3] -= 2.0f*x1*p1;
    }
    v42 = x1;
  }
  e[2] = a[3][2];
  d[0]=a[0][0]; d[1]=a[1][1]; d[2]=a[2][2]; d[3]=a[3][3];
  float z[4][4] = {{1,0,0,0},{0,1,0,0},{0,0,1,0},{0,0,0,1}};
  const float eps = F32_EPS;
  const float eps2 = F32_EPS2;
  const float safmin = F32_SAFMIN;
  int jtot = 0;
  const int nmaxit = 120;
  int l1 = 0;
  bool fail = false;
  while (!fail){
    if (l1 > 3) break;
    if (l1 > 0) e[l1-1] = 0.0f;
    int lend = 3;
    for (int mm = l1; mm <= 2; ++mm){
      float tst = fabsf(e[mm]);
      if (tst == 0.0f){ lend = mm; break; }
      if (tst <= (sqrtf(fabsf(d[mm]))*sqrtf(fabsf(d[mm+1])))*eps){ e[mm] = 0.0f; lend = mm; break; }
    }
    int l = l1;
    int lsv = l, lendsv = lend;
    l1 = lend + 1;
    if (lend == l) continue;
    float anorm = fabsf(d[l]);
    for (int ii=l+1; ii<=lend; ++ii) anorm = fmaxf(anorm, fabsf(d[ii]));
    for (int ii=l; ii<lend; ++ii)    anorm = fmaxf(anorm, fabsf(e[ii]));
    if (anorm == 0.0f) continue;
    if (fabsf(d[lend]) < fabsf(d[l])){ lend = lsv; l = lendsv; }
    if (lend > l){
      for (;;){
        int m = lend;
        if (l != lend){
          for (int mm=l; mm<=lend-1; ++mm){
            float tst = e[mm]*e[mm];
            if (tst <= (eps2*fabsf(d[mm]))*fabsf(d[mm+1]) + safmin){ m = mm; break; }
          }
        }
        if (m < lend) e[m] = 0.0f;
        float p = d[l];
        if (m == l){
          d[l] = p; ++l;
          if (l <= lend) continue;
          break;
        }
        if (m == l+1){
          float rt1, rt2, c, s;
          slaev2(d[l], e[l], d[l+1], rt1, rt2, c, s);
          #pragma unroll
          for (int r2=0;r2<4;r2++){
            float t_ = z[r2][l+1];
            z[r2][l+1] = c*t_ - s*z[r2][l];
            z[r2][l]   = s*t_ + c*z[r2][l];
          }
          d[l]=rt1; d[l+1]=rt2; e[l]=0.0f;
          l += 2;
          if (l <= lend) continue;
          break;
        }
        if (jtot == nmaxit){ fail = true; break; }
        ++jtot;
        float g = (d[l+1]-p)/(2.0f*e[l]);
        float r_ = slapy2(g, 1.0f);
        g = d[m] - p + e[l]/(g + s_sign(r_, g));
        float s = 1.0f, c = 1.0f;
        p = 0.0f;
        float csv[3], snv[3];
        for (int i=m-1; i>=l; --i){
          float f = s*e[i], b = c*e[i];
          slartg(g, f, c, s, r_);
          if (i != m-1) e[i+1] = r_;
          g = d[i+1] - p;
          r_ = (d[i]-g)*s + 2.0f*c*b;
          p = s*r_;
          d[i+1] = g + p;
          g = c*r_ - b;
          csv[i] = c; snv[i] = -s;
        }
        for (int i=m-1; i>=l; --i){
          float cc = csv[i], ss = snv[i];
          #pragma unroll
          for (int r2=0;r2<4;r2++){
            float t_ = z[r2][i+1];
            z[r2][i+1] = cc*t_ - ss*z[r2][i];
            z[r2][i]   = ss*t_ + cc*z[r2][i];
          }
        }
        d[l] -= p; e[l] = g;
      }
    } else {
      for (;;){
        int m = lend;
        if (l != lend){
          for (int mm=l; mm>=lend+1; --mm){
            float tst = e[mm-1]*e[mm-1];
            if (tst <= (eps2*fabsf(d[mm]))*fabsf(d[mm-1]) + safmin){ m = mm; break; }
          }
        }
        if (m > lend) e[m-1] = 0.0f;
        float p = d[l];
        if (m == l){
          d[l] = p; --l;
          if (l >= lend) continue;
          break;
        }
        if (m == l-1){
          float rt1, rt2, c, s;
          slaev2(d[l-1], e[l-1], d[l], rt1, rt2, c, s);
          #pragma unroll
          for (int r2=0;r2<4;r2++){
            float t_ = z[r2][l];
            z[r2][l]   = c*t_ - s*z[r2][l-1];
            z[r2][l-1] = s*t_ + c*z[r2][l-1];
          }
          d[l-1]=rt1; d[l]=rt2; e[l-1]=0.0f;
          l -= 2;
          if (l >= lend) continue;
          break;
        }
        if (jtot == nmaxit){ fail = true; break; }
        ++jtot;
        float g = (d[l-1]-p)/(2.0f*e[l-1]);
        float r_ = slapy2(g, 1.0f);
        g = d[m] - p + e[l-1]/(g + s_sign(r_, g));
        float s = 1.0f, c = 1.0f;
        p = 0.0f;
        float csv[3], snv[3];
        for (int i=m; i<=l-1; ++i){
          float f = s*e[i], b = c*e[i];
          slartg(g, f, c, s, r_);
          if (i != m) e[i-1] = r_;
          g = d[i] - p;
          r_ = (d[i+1]-g)*s + 2.0f*c*b;
          p = s*r_;
          d[i] = g + p;
          g = c*r_ - b;
          csv[i] = c; snv[i] = s;
        }
        for (int i=m; i<=l-1; ++i){
          float cc = csv[i], ss = snv[i];
          #pragma unroll
          for (int r2=0;r2<4;r2++){
            float t_ = z[r2][i+1];
            z[r2][i+1] = cc*t_ - ss*z[r2][i];
            z[r2][i]   = ss*t_ + cc*z[r2][i];
          }
        }
        d[l] -= p; e[l-1] = g;
      }
    }
  }
  for (int ii=1; ii<4; ++ii){
    int i0 = ii-1, k0 = i0;
    float p = d[i0];
    for (int j2=ii; j2<4; ++j2) if (d[j2] < p){ k0 = j2; p = d[j2]; }
    if (k0 != i0){
      d[k0] = d[i0]; d[i0] = p;
      #pragma unroll
      for (int r2=0;r2<4;r2++){ float t_ = z[r2][i0]; z[r2][i0] = z[r2][k0]; z[r2][k0] = t_; }
    }
  }
  float w0 = z[0][3], w1 = z[1][3], w2 = z[2][3], w3 = z[3][3];
  if (tau1 != 0.0f){
    float dv = w2 + v42*w3;
    w2 -= tau1*dv;
    w3 -= tau1*dv*v42;
  }
  if (tau0 != 0.0f){
    float dv = w1 + v31*w2 + v41*w3;
    w1 -= tau0*dv;
    w2 -= tau0*dv*v31;
    w3 -= tau0*dv*v41;
  }
  q[0]=w0; q[1]=w1; q[2]=w2; q[3]=w3;
}

// ---------------- kernels ----------------
__global__ void fill_kernel(float* __restrict__ p, int nelem, float val){
  int i = blockIdx.x*blockDim.x + threadIdx.x;
  if (i < nelem) p[i] = val;
}

__global__ void rigid_kernel(const float* __restrict__ bb, float* __restrict__ Rg, float* __restrict__ tg){
  int n = blockIdx.x*blockDim.x + threadIdx.x;
  if (n >= NN) return;
  const float* p = bb + (size_t)n*9;
  float nx=p[0],ny=p[1],nz=p[2], cax=p[3],cay=p[4],caz=p[5], cx=p[6],cy=p[7],cz=p[8];
  float e1x=cx-cax, e1y=cy-cay, e1z=cz-caz;
  float n1 = sqrtf(e1x*e1x+e1y*e1y+e1z*e1z);
  e1x/=n1; e1y/=n1; e1z/=n1;
  float ux=nx-cax, uy=ny-cay, uz=nz-caz;
  float du = ux*e1x+uy*e1y+uz*e1z;
  float e2x=ux-du*e1x, e2y=uy-du*e1y, e2z=uz-du*e1z;
  float n2 = sqrtf(e2x*e2x+e2y*e2y+e2z*e2z);
  e2x/=n2; e2y/=n2; e2z/=n2;
  float e3x=e1y*e2z-e1z*e2y, e3y=e1z*e2x-e1x*e2z, e3z=e1x*e2y-e1y*e2x;
  float* R = Rg + (size_t)n*9;
  R[0]=e1x; R[1]=e2x; R[2]=e3x;
  R[3]=e1y; R[4]=e2y; R[5]=e3y;
  R[6]=e1z; R[7]=e2z; R[8]=e3z;
  tg[(size_t)n*3+0]=cax; tg[(size_t)n*3+1]=cay; tg[(size_t)n*3+2]=caz;
}

__global__ __launch_bounds__(256) void ln_kernel(const float* __restrict__ x,
    const float* __restrict__ g, const float* __restrict__ b, float* __restrict__ xln){
  int n = blockIdx.x, t = threadIdx.x;
  __shared__ float rbuf[256];
  float v[5];
  float s = 0.0f;
  #pragma unroll
  for (int i=0;i<5;i++){ v[i] = x[(size_t)n*IND + t + i*256]; s += v[i]; }
  float mu = bsumf(s, rbuf)*(1.0f/IND);
  float pv = 0.0f;
  #pragma unroll
  for (int i=0;i<5;i++){ float dd = v[i]-mu; pv += dd*dd; }
  float var = bsumf(pv, rbuf)*(1.0f/IND);
  float rs = 1.0f/sqrtf(var + 1e-5f);
  #pragma unroll
  for (int i=0;i<5;i++){
    int k = t + i*256;
    xln[(size_t)n*IND + k] = g[k]*((v[i]-mu)*rs) + b[k];
  }
}

// emb0 with LDS staging of the 8 xln rows (arithmetic identical).
__global__ __launch_bounds__(256) void emb0_kernel(const float* __restrict__ xln,
    const float* __restrict__ W, const float* __restrict__ bias, float* __restrict__ emb){
  int n0 = blockIdx.x*8, j = threadIdx.x;
  __shared__ float s_x[8][IND];   // 40 KB
  for (int idx=j; idx<8*IND; idx+=256){
    int i = idx/IND, k = idx - i*IND;
    s_x[i][k] = xln[(size_t)(n0+i)*IND + k];
  }
  __syncthreads();
  float acc[8];
  #pragma unroll
  for (int i=0;i<8;i++) acc[i] = bias[j];
  for (int k=0;k<IND;k+=4){
    float w0=W[(size_t)(k+0)*EMB+j], w1=W[(size_t)(k+1)*EMB+j], w2=W[(size_t)(k+2)*EMB+j], w3=W[(size_t)(k+3)*EMB+j];
    #pragma unroll
    for (int i=0;i<8;i++){
      const float* xp = &s_x[i][k];
      acc[i] += xp[0]*w0 + xp[1]*w1 + xp[2]*w2 + xp[3]*w3;
    }
  }
  #pragma unroll
  for (int i=0;i<8;i++) emb[(size_t)(n0+i)*EMB + j] = acc[i];
}

__global__ __launch_bounds__(64) void edge_kernel(const float* __restrict__ bb,
    const float* __restrict__ Rg, const float* __restrict__ tg,
    const int* __restrict__ col, float* __restrict__ Redge, float* __restrict__ eattr){
  int e = blockIdx.x*64 + threadIdx.x;
  if (e >= EE) return;
  int i = e/KK;
  int jn = col[e];
  float Ri[9], Rj[9];
  #pragma unroll
  for (int a=0;a<9;a++){ Ri[a]=Rg[(size_t)i*9+a]; Rj[a]=Rg[(size_t)jn*9+a]; }
  float dt0 = tg[(size_t)jn*3+0]-tg[(size_t)i*3+0];
  float dt1 = tg[(size_t)jn*3+1]-tg[(size_t)i*3+1];
  float dt2 = tg[(size_t)jn*3+2]-tg[(size_t)i*3+2];
  float Re[9];
  #pragma unroll
  for (int a=0;a<3;a++){
    #pragma unroll
    for (int c=0;c<3;c++)
      Re[a*3+c] = Ri[0+a]*Rj[0+c] + Ri[3+a]*Rj[3+c] + Ri[6+a]*Rj[6+c];
  }
  float te0 = Ri[0]*dt0 + Ri[3]*dt1 + Ri[6]*dt2;
  float te1 = Ri[1]*dt0 + Ri[4]*dt1 + Ri[7]*dt2;
  float te2 = Ri[2]*dt0 + Ri[5]*dt1 + Ri[8]*dt2;
  float xx=Re[0], xy=Re[1], xz=Re[2], yx=Re[3], yy=Re[4], yz=Re[5], zx=Re[6], zy=Re[7], zz=Re[8];
  float km[4][4];
  km[0][0]=(xx+yy+zz)/3.0f; km[0][1]=(zy-yz)/3.0f;    km[0][2]=(xz-zx)/3.0f;    km[0][3]=(yx-xy)/3.0f;
  km[1][0]=km[0][1];        km[1][1]=(xx-yy-zz)/3.0f; km[1][2]=(xy+yx)/3.0f;    km[1][3]=(xz+zx)/3.0f;
  km[2][0]=km[0][2];        km[2][1]=km[1][2];        km[2][2]=(yy-xx-zz)/3.0f; km[2][3]=(yz+zy)/3.0f;
  km[3][0]=km[0][3];        km[3][1]=km[1][3];        km[3][2]=km[2][3];        km[3][3]=(zz-xx-yy)/3.0f;
  float q[4];
  sym4_quat_f32(km, q);
  float* ea = eattr + (size_t)e*EAP;
  ea[0]=q[0]; ea[1]=q[1]; ea[2]=q[2]; ea[3]=q[3];
  ea[4]=te0;  ea[5]=te1;  ea[6]=te2;
  int cd = i - jn; if (cd < 0) cd = -cd;
  ea[7] = logf((float)cd + 1.0f);
  ea[8] = logf(sqrtf(te0*te0+te1*te1+te2*te2) + 1e-8f);
  const float* bi = bb + (size_t)i*9;
  const float* bj = bb + (size_t)jn*9;
  int idx = 9;
  #pragma unroll
  for (int a=0;a<3;a++){
    float ax=bi[a*3+0], ay=bi[a*3+1], az=bi[a*3+2];
    #pragma unroll
    for (int b2=0;b2<3;b2++){
      float dx=ax-bj[b2*3+0], dy=ay-bj[b2*3+1], dz=az-bj[b2*3+2];
      float dd = sqrtf(fmaxf(dx*dx+dy*dy+dz*dz, 1e-12f));
      #pragma unroll
      for (int kb=0;kb<16;kb++){
        float muv = 1.3333334f*(float)kb;
        float df = dd - muv;
        ea[idx] = expf(-0.5f*df*df);
        idx++;
      }
    }
  }
  ea[153]=0.0f; ea[154]=0.0f; ea[155]=0.0f;
  #pragma unroll
  for (int a=0;a<9;a++) Redge[(size_t)e*9+a] = Re[a];
}

// Fused h1 + h2 + LN + vu per node-block. Arithmetic bit-identical to R8's
// h1_kernel -> h2_kernel -> vu part of vu_qr_kernel (incl. inlined vjr).
__global__ __launch_bounds__(256, 3) void fused_kernel(
    const float* __restrict__ emb_in, const float* __restrict__ v_in,
    const float* __restrict__ Redge, const float* __restrict__ eattr,
    const int* __restrict__ col,
    const float* __restrict__ W1, const float* __restrict__ b1,
    const float* __restrict__ W2, const float* __restrict__ b2,
    const float* __restrict__ W3, const float* __restrict__ b3,
    const float* __restrict__ vW,
    const float* __restrict__ lng, const float* __restrict__ lnb,
    float* __restrict__ emb_out, float* __restrict__ vu_out){
  int n = blockIdx.x, j = threadIdx.x;
  size_t e0 = (size_t)n*KK;
  __shared__ float s_big[KK*EMB];    // 30 KB: s_emb in phase B, s_h1 in phase C
  __shared__ float s_ea [KK][EAP];   // 18.3 KB
  __shared__ float s_vjr[KK][16];    // 1.9 KB
  __shared__ float s_xi [EMB];
  __shared__ float s_vi [V3];
  __shared__ float sbuf[EMB];
  __shared__ float rbuf[256];

  // ---- staging (coalesced) ----
  #pragma unroll
  for (int e=0;e<KK;e++){
    int cj = col[e0+e];
    s_big[e*EMB + j] = emb_in[(size_t)cj*EMB + j];
  }
  s_xi[j] = emb_in[(size_t)n*EMB + j];
  if (j < V3) s_vi[j] = v_in[(size_t)n*V3 + j];
  for (int idx=j; idx<KK*EAP; idx+=256){
    int e = idx/EAP, kk = idx - e*EAP;
    s_ea[e][kk] = eattr[(e0+e)*EAP + kk];
  }
  // inlined vjr (same expression as old vjr_kernel)
  for (int idx=j; idx<KK*16; idx+=256){
    int e = idx>>4, r = idx&15;
    if (r < V3){
      int m = r/3, ii = r - m*3;
      int cj = col[e0+e];
      const float* Rp = Redge + (e0+e)*9;
      const float* vp = v_in + (size_t)cj*V3 + m*3;
      s_vjr[e][r] = Rp[ii*3+0]*vp[0] + Rp[ii*3+1]*vp[1] + Rp[ii*3+2]*vp[2];
    }
  }
  __syncthreads();

  // ---- phase B: h1 ----
  float csh = b1[j];
  {
    for (int k=0;k<EMB;k+=4){
      float w0=W1[(size_t)(k+0)*EMB+j], w1=W1[(size_t)(k+1)*EMB+j], w2=W1[(size_t)(k+2)*EMB+j], w3=W1[(size_t)(k+3)*EMB+j];
      csh += s_xi[k+0]*w0 + s_xi[k+1]*w1 + s_xi[k+2]*w2 + s_xi[k+3]*w3;
    }
    #pragma unroll
    for (int r=0;r<V3;r++) csh += s_vi[r]*(W1[(size_t)(512+r)*EMB+j] + W1[(size_t)(542+r)*EMB+j]);
  }
  float acc[KK];
  #pragma unroll
  for (int e=0;e<KK;e++) acc[e] = csh;
  #pragma unroll
  for (int eg=0; eg<KK; eg+=15){
    for (int k=0;k<EMB;k+=4){
      float w0=W1[(size_t)(256+k)*EMB+j], w1=W1[(size_t)(257+k)*EMB+j], w2=W1[(size_t)(258+k)*EMB+j], w3=W1[(size_t)(259+k)*EMB+j];
      #pragma unroll
      for (int qq=0;qq<15;qq++){
        const float* xp = &s_big[(eg+qq)*EMB + k];
        acc[eg+qq] += xp[0]*w0 + xp[1]*w1 + xp[2]*w2 + xp[3]*w3;
      }
    }
  }
  {
    float wv[V3];
    #pragma unroll
    for (int r=0;r<V3;r++) wv[r] = W1[(size_t)(527+r)*EMB+j] - W1[(size_t)(542+r)*EMB+j];
    #pragma unroll
    for (int e=0;e<KK;e++){
      float a = acc[e];
      #pragma unroll
      for (int r=0;r<V3;r++) a += s_vjr[e][r]*wv[r];
      acc[e] = a;
    }
  }
  #pragma unroll
  for (int eg=0; eg<KK; eg+=15){
    for (int k=0;k<152;k+=4){
      float w0=W1[(size_t)(557+k)*EMB+j], w1=W1[(size_t)(558+k)*EMB+j], w2=W1[(size_t)(559+k)*EMB+j], w3=W1[(size_t)(560+k)*EMB+j];
      #pragma unroll
      for (int qq=0;qq<15;qq++){
        const float* ap = &s_ea[eg+qq][k];
        acc[eg+qq] += ap[0]*w0 + ap[1]*w1 + ap[2]*w2 + ap[3]*w3;
      }
    }
    float wl = W1[(size_t)709*EMB+j];
    #pragma unroll
    for (int qq=0;qq<15;qq++) acc[eg+qq] += s_ea[eg+qq][152]*wl;
  }
  // h1 -> LDS (reuse s_big; all reads of s_emb are complete for THIS thread's
  // acc, but other threads may lag — barrier first)
  __syncthreads();
  #pragma unroll
  for (int e=0;e<KK;e++) s_big[e*EMB + j] = gelu_f(acc[e]);
  __syncthreads();

  // ---- phase C: h2 ----
  float acc2[KK];
  #pragma unroll
  for (int e=0;e<KK;e++) acc2[e] = b2[j];
  #pragma unroll
  for (int eg=0; eg<KK; eg+=15){
    for (int k=0;k<EMB;k+=4){
      float w0=W2[(size_t)(k+0)*EMB+j], w1=W2[(size_t)(k+1)*EMB+j], w2=W2[(size_t)(k+2)*EMB+j], w3=W2[(size_t)(k+3)*EMB+j];
      #pragma unroll
      for (int qq=0;qq<15;qq++){
        const float* hp = &s_big[(eg+qq)*EMB + k];
        acc2[eg+qq] += hp[0]*w0 + hp[1]*w1 + hp[2]*w2 + hp[3]*w3;
      }
    }
  }
  float s = 0.0f;
  #pragma unroll
  for (int e=0;e<KK;e++) s += gelu_f(acc2[e]);
  sbuf[j] = s;
  __syncthreads();
  float ag = 0.0f;
  for (int k=0;k<EMB;k+=4){
    float4 s4 = *(const float4*)&sbuf[k];
    ag += s4.x*W3[(size_t)(k+0)*EMB+j] + s4.y*W3[(size_t)(k+1)*EMB+j]
        + s4.z*W3[(size_t)(k+2)*EMB+j] + s4.w*W3[(size_t)(k+3)*EMB+j];
  }
  ag = ag*(1.0f/30.0f) + b3[j];
  float u = emb_in[(size_t)n*EMB+j] + ag;
  float mu = bsumf(u, rbuf)*(1.0f/EMB);
  float dl = u - mu;
  float var = bsumf(dl*dl, rbuf)*(1.0f/EMB);
  float rs = 1.0f/sqrtf(var + 1e-5f);
  float y = lng[j]*dl*rs + lnb[j];
  emb_out[(size_t)n*EMB+j] = y;
  sbuf[j] = y;            // safe: all sbuf reads completed before bsumf barriers
  __syncthreads();
  // ---- vu (same arithmetic as R8 vu_qr's per-node part) ----
  if (j < V3){
    float a = s_vi[j];
    for (int k=0;k<EMB;k++){
      a += sbuf[k]*vW[k*V3+j];
    }
    #pragma unroll
    for (int r=0;r<V3;r++) a += s_vi[r]*vW[(EMB+r)*V3+j];
    vu_out[(size_t)n*V3+j] = a;
  }
}

// Pure QR per graph (f32 sgeqr2/sorg2r, raw LAPACK signs) — identical to R8.
__global__ __launch_bounds__(256) void qr_kernel(
    const float* __restrict__ vu_in, float* __restrict__ vout){
  int g = blockIdx.x, t = threadIdx.x;
  __shared__ float A[QRM*QRN];
  __shared__ float meanv[V3];
  __shared__ float taus[QRN];
  __shared__ float sh[2];
  int n = g*LSZ + t;
  #pragma unroll
  for (int j=0;j<V3;j++) A[t*V3+j] = vu_in[(size_t)n*V3 + j];
  __syncthreads();
  if (t < V3){
    float s = 0.0f;
    for (int l0=0;l0<LSZ;l0++) s += A[l0*V3+t];
    meanv[t] = s/(float)LSZ;
  }
  __syncthreads();
  #pragma unroll
  for (int j=0;j<V3;j++) A[t*V3+j] -= meanv[j];
  __syncthreads();
  // ---- sgeqr2 ----
  for (int i=0;i<QRN;i++){
    if (t == 0){
      float s0=0,s1=0,s2=0,s3=0;
      int r=i+1;
      for (; r+3<QRM; r+=4){
        float x0=A[r*QRN+i], x1=A[(r+1)*QRN+i], x2=A[(r+2)*QRN+i], x3=A[(r+3)*QRN+i];
        s0+=x0*x0; s1+=x1*x1; s2+=x2*x2; s3+=x3*x3;
      }
      for (; r<QRM; r++){ float x=A[r*QRN+i]; s0+=x*x; }
      float xn2 = (s0+s1)+(s2+s3);
      float alpha = A[i*QRN+i];
      float taui = 0.0f, sc = 1.0f;
      if (xn2 != 0.0f){
        float beta = -s_sign(slapy2(alpha, sqrtf(xn2)), alpha);
        taui = (beta - alpha)/beta;
        sc = 1.0f/(alpha - beta);
      }
      taus[i] = taui; sh[0] = sc;
    }
    __syncthreads();
    {
      float sc = sh[0];
      for (int r=i+1+t; r<QRM; r+=256) A[r*QRN+i] *= sc;
    }
    __syncthreads();
    for (int j=i+1;j<QRN;j++){
      if (t == 0){
        float s0=A[i*QRN+j], s1=0,s2=0,s3=0;
        int r=i+1;
        for (; r+3<QRM; r+=4){
          s0 += A[r*QRN+i]*A[r*QRN+j];
          s1 += A[(r+1)*QRN+i]*A[(r+1)*QRN+j];
          s2 += A[(r+2)*QRN+i]*A[(r+2)*QRN+j];
          s3 += A[(r+3)*QRN+i]*A[(r+3)*QRN+j];
        }
        for (; r<QRM; r++) s0 += A[r*QRN+i]*A[r*QRN+j];
        sh[0] = taus[i]*((s0+s1)+(s2+s3));
      }
      __syncthreads();
      {
        float w = sh[0];
        for (int r=i+t; r<QRM; r+=256){
          float vr = (r==i) ? 1.0f : A[r*QRN+i];
          A[r*QRN+j] -= w*vr;
        }
      }
      __syncthreads();
    }
  }
  // ---- sorg2r ----
  for (int i=QRN-1;i>=0;i--){
    for (int j=i+1;j<QRN;j++){
      if (t == 0){
        float s0=A[i*QRN+j], s1=0,s2=0,s3=0;
        int r=i+1;
        for (; r+3<QRM; r+=4){
          s0 += A[r*QRN+i]*A[r*QRN+j];
          s1 += A[(r+1)*QRN+i]*A[(r+1)*QRN+j];
          s2 += A[(r+2)*QRN+i]*A[(r+2)*QRN+j];
          s3 += A[(r+3)*QRN+i]*A[(r+3)*QRN+j];
        }
        for (; r<QRM; r++) s0 += A[r*QRN+i]*A[r*QRN+j];
        sh[0] = taus[i]*((s0+s1)+(s2+s3));
      }
      __syncthreads();
      {
        float w = sh[0];
        for (int r=i+t; r<QRM; r+=256){
          float vr = (r==i) ? 1.0f : A[r*QRN+i];
          A[r*QRN+j] -= w*vr;
        }
      }
      __syncthreads();
    }
    {
      float taui = taus[i];
      for (int r=i+1+t; r<QRM; r+=256) A[r*QRN+i] *= -taui;
    }
    __syncthreads();
    if (t == 0) A[i*QRN+i] = 1.0f - taus[i];
    if (t < i) A[t*QRN+i] = 0.0f;
    __syncthreads();
  }
  for (int idx=t; idx<QRM*QRN; idx+=256)
    vout[(size_t)g*LSZ*V3 + idx] = 16.0f*A[idx];
}

__global__ __launch_bounds__(256) void final_kernel(const float* __restrict__ embf,
    const float* __restrict__ vf, const float* __restrict__ Rg, float* __restrict__ out){
  int n = blockIdx.x, t = threadIdx.x;
  out[(size_t)n*EMB + t] = embf[(size_t)n*EMB + t];
  if (t < V3){
    int m = t/3, ii = t - m*3;
    const float* Rp = Rg + (size_t)n*9;
    const float* vp = vf + (size_t)n*V3 + m*3;
    float val = Rp[ii*3+0]*vp[0] + Rp[ii*3+1]*vp[1] + Rp[ii*3+2]*vp[2];
    out[(size_t)NN*EMB + (size_t)n*V3 + t] = val;
  }
}

// ---------------- host ----------------
extern "C" void kernel_launch(void* const* d_in, const int* in_sizes, int n_in,
                              void* d_out, int out_size, void* d_ws, size_t ws_size,
                              hipStream_t stream){
  (void)in_sizes; (void)n_in; (void)out_size; (void)ws_size;
  const float* x       = (const float*)d_in[0];
  const float* bb      = (const float*)d_in[1];
  const float* in_ln_g = (const float*)d_in[2];
  const float* in_ln_b = (const float*)d_in[3];
  const float* in_W    = (const float*)d_in[4];
  const float* in_b    = (const float*)d_in[5];
  const float* msg_W1  = (const float*)d_in[6];
  const float* msg_b1  = (const float*)d_in[7];
  const float* msg_W2  = (const float*)d_in[8];
  const float* msg_b2  = (const float*)d_in[9];
  const float* msg_W3  = (const float*)d_in[10];
  const float* msg_b3  = (const float*)d_in[11];
  const float* vect_W  = (const float*)d_in[12];
  const float* ln_g    = (const float*)d_in[13];
  const float* ln_b    = (const float*)d_in[14];
  const int*   col     = (const int*)d_in[16];

  char* p = (char*)d_ws;
  auto alloc = [&](size_t bytes)->void*{ void* r = (void*)p; p += (bytes + 255) & ~(size_t)255; return r; };
  float*  Rg    = (float*) alloc((size_t)NN*9*4);
  float*  tg    = (float*) alloc((size_t)NN*3*4);
  float*  xln   = (float*) alloc((size_t)NN*IND*4);
  float*  eA    = (float*) alloc((size_t)NN*EMB*4);
  float*  eB    = (float*) alloc((size_t)NN*EMB*4);
  float*  vA    = (float*) alloc((size_t)NN*V3*4);
  float*  vB    = (float*) alloc((size_t)NN*V3*4);
  float*  vu    = (float*) alloc((size_t)NN*V3*4);
  float*  Redge = (float*) alloc((size_t)EE*9*4);
  float*  eattr = (float*) alloc((size_t)EE*EAP*4);

  const int NV = NN*V3;
  fill_kernel<<<(NV+255)/256, 256, 0, stream>>>(vA, NV, 0.0f);
  rigid_kernel<<<(NN+63)/64, 64, 0, stream>>>(bb, Rg, tg);
  ln_kernel<<<NN, 256, 0, stream>>>(x, in_ln_g, in_ln_b, xln);
  emb0_kernel<<<NN/8, 256, 0, stream>>>(xln, in_W, in_b, eA);
  edge_kernel<<<(EE+63)/64, 64, 0, stream>>>(bb, Rg, tg, col, Redge, eattr);

  float* ein = eA; float* eout = eB; float* vin = vA; float* vout = vB;
  for (int l=0; l<3; ++l){
    fused_kernel<<<NN, 256, 0, stream>>>(ein, vin, Redge, eattr, col,
        msg_W1 + (size_t)l*710*EMB, msg_b1 + (size_t)l*EMB,
        msg_W2 + (size_t)l*EMB*EMB, msg_b2 + (size_t)l*EMB,
        msg_W3 + (size_t)l*EMB*EMB, msg_b3 + (size_t)l*EMB,
        vect_W + (size_t)l*(EMB+V3)*V3,
        ln_g + (size_t)l*EMB, ln_b + (size_t)l*EMB, eout, vu);
    qr_kernel<<<NG, 256, 0, stream>>>(vu, vout);
    float* tmp = ein; ein = eout; eout = tmp;
    tmp = vin; vin = vout; vout = tmp;
  }
  final_kernel<<<NN, 256, 0, stream>>>(ein, vin, Rg, (float*)d_out);
}

// Round 10
// 2394.554 us; speedup vs baseline: 1.5485x; 1.0698x over previous
//
#include <hip/hip_runtime.h>
#include <hip/hip_bf16.h>

#define NG   8
#define LSZ  256
#define NN   2048
#define KK   30
#define EE   61440
#define IND  1280
#define EMB  256
#define V3   15
#define EAP  156
#define QRM  768
#define QRN  5

#define F32_EPS    5.9604645e-08f
#define F32_EPS2   3.5527137e-15f
#define F32_SAFMIN 1.17549435e-38f

__device__ __forceinline__ float bsumf(float v, float* rbuf){
  int t = threadIdx.x;
  __syncthreads();
  rbuf[t] = v;
  __syncthreads();
  for (int s=128; s>0; s>>=1){
    if (t < s) rbuf[t] += rbuf[t+s];
    __syncthreads();
  }
  float r = rbuf[0];
  __syncthreads();
  return r;
}
__device__ __forceinline__ float gelu_f(float x){
  return 0.5f*x*(1.0f + erff(x*0.70710678f));
}
__device__ __forceinline__ float s_sign(float a, float b){ return (b >= 0.0f) ? fabsf(a) : -fabsf(a); }
__device__ __forceinline__ float slapy2(float x, float y){
  float xa = fabsf(x), ya = fabsf(y);
  float w = fmaxf(xa, ya), z = fminf(xa, ya);
  if (z == 0.0f) return w;
  float t = z/w;
  return w*sqrtf(1.0f + t*t);
}
// LAPACK >=3.10 slartg (f32)
__device__ void slartg(float f, float g, float& c, float& s, float& r){
  const float safmin = F32_SAFMIN;
  const float safmax = 8.5070592e+37f;
  const float rtmin  = 1.0842022e-19f;
  const float rtmax  = 6.5243586e+18f;
  float f1 = fabsf(f), g1 = fabsf(g);
  if (g == 0.0f){ c = 1.0f; s = 0.0f; r = f; }
  else if (f == 0.0f){ c = 0.0f; s = (g >= 0.0f ? 1.0f : -1.0f); r = g1; }
  else {
    if (f1 > rtmin && f1 < rtmax && g1 > rtmin && g1 < rtmax){
      float d = sqrtf(f*f + g*g);
      c = f1/d;
      r = (f >= 0.0f ? d : -d);
      s = g/r;
    } else {
      float u = fminf(safmax, fmaxf(safmin, fmaxf(f1,g1)));
      float fs = f/u, gs = g/u;
      float d = sqrtf(fs*fs + gs*gs);
      c = fabsf(fs)/d;
      r = (f >= 0.0f ? d : -d);
      s = gs/r;
      r = r*u;
    }
  }
}
__device__ void slaev2(float a, float b, float c, float& rt1, float& rt2, float& cs1, float& sn1){
  float sm = a + c, df = a - c, adf = fabsf(df), tb = b + b, ab = fabsf(tb);
  float acmx, acmn;
  if (fabsf(a) > fabsf(c)) { acmx=a; acmn=c; } else { acmx=c; acmn=a; }
  float rt;
  if (adf > ab){ float t = ab/adf; rt = adf*sqrtf(1.0f+t*t); }
  else if (adf < ab){ float t = adf/ab; rt = ab*sqrtf(1.0f+t*t); }
  else rt = ab*sqrtf(2.0f);
  int sgn1;
  if (sm < 0.0f){ rt1 = 0.5f*(sm-rt); sgn1 = -1; rt2 = (acmx/rt1)*acmn - (b/rt1)*b; }
  else if (sm > 0.0f){ rt1 = 0.5f*(sm+rt); sgn1 = 1; rt2 = (acmx/rt1)*acmn - (b/rt1)*b; }
  else { rt1 = 0.5f*rt; rt2 = -0.5f*rt; sgn1 = 1; }
  float cs; int sgn2;
  if (df >= 0.0f){ cs = df + rt; sgn2 = 1; } else { cs = df - rt; sgn2 = -1; }
  float acs = fabsf(cs);
  if (acs > ab){
    float ct = -tb/cs; sn1 = 1.0f/sqrtf(1.0f+ct*ct); cs1 = ct*sn1;
  } else {
    if (ab == 0.0f){ cs1 = 1.0f; sn1 = 0.0f; }
    else { float tn = -cs/tb; cs1 = 1.0f/sqrtf(1.0f+tn*tn); sn1 = tn*cs1; }
  }
  if (sgn1 == sgn2){ float tn = cs1; cs1 = -sn1; sn1 = tn; }
}

// f32 ssytd2('L') + ssteqr('I') for 4x4; returns eigvec of largest eigenvalue.
__device__ void sym4_quat_f32(float (&a)[4][4], float* q){
  float d[4], e[3];
  float tau0 = 0.0f, tau1 = 0.0f;
  float v31 = 0.0f, v41 = 0.0f, v42 = 0.0f;
  {
    float alpha = a[1][0];
    float x1 = a[2][0], x2 = a[3][0];
    float xnorm = sqrtf(x1*x1 + x2*x2);
    if (xnorm == 0.0f){ tau0 = 0.0f; e[0] = alpha; }
    else {
      float beta = -s_sign(slapy2(alpha, xnorm), alpha);
      tau0 = (beta - alpha)/beta;
      float sc = 1.0f/(alpha - beta);
      x1 *= sc; x2 *= sc;
      e[0] = beta;
      float p0 = tau0*(a[1][1] + a[2][1]*x1 + a[3][1]*x2);
      float p1 = tau0*(a[2][1] + a[2][2]*x1 + a[3][2]*x2);
      float p2 = tau0*(a[3][1] + a[3][2]*x1 + a[3][3]*x2);
      float al = -0.5f*tau0*(p0 + p1*x1 + p2*x2);
      p0 += al; p1 += al*x1; p2 += al*x2;
      a[1][1] -= 2.0f*p0;
      a[2][1] -= x1*p0 + p1;
      a[3][1] -= x2*p0 + p2;
      a[2][2] -= 2.0f*x1*p1;
      a[3][2] -= x2*p1 + p2*x1;
      a[3][3] -= 2.0f*x2*p2;
    }
    v31 = x1; v41 = x2;
  }
  {
    float alpha = a[2][1];
    float x1 = a[3][1];
    float xnorm = fabsf(x1);
    if (xnorm == 0.0f){ tau1 = 0.0f; e[1] = alpha; }
    else {
      float beta = -s_sign(slapy2(alpha, xnorm), alpha);
      tau1 = (beta - alpha)/beta;
      x1 *= 1.0f/(alpha - beta);
      e[1] = beta;
      float p0 = tau1*(a[2][2] + a[3][2]*x1);
      float p1 = tau1*(a[3][2] + a[3][3]*x1);
      float al = -0.5f*tau1*(p0 + p1*x1);
      p0 += al; p1 += al*x1;
      a[2][2] -= 2.0f*p0;
      a[3][2] -= x1*p0 + p1;
      a[3][3] -= 2.0f*x1*p1;
    }
    v42 = x1;
  }
  e[2] = a[3][2];
  d[0]=a[0][0]; d[1]=a[1][1]; d[2]=a[2][2]; d[3]=a[3][3];
  float z[4][4] = {{1,0,0,0},{0,1,0,0},{0,0,1,0},{0,0,0,1}};
  const float eps = F32_EPS;
  const float eps2 = F32_EPS2;
  const float safmin = F32_SAFMIN;
  int jtot = 0;
  const int nmaxit = 120;
  int l1 = 0;
  bool fail = false;
  while (!fail){
    if (l1 > 3) break;
    if (l1 > 0) e[l1-1] = 0.0f;
    int lend = 3;
    for (int mm = l1; mm <= 2; ++mm){
      float tst = fabsf(e[mm]);
      if (tst == 0.0f){ lend = mm; break; }
      if (tst <= (sqrtf(fabsf(d[mm]))*sqrtf(fabsf(d[mm+1])))*eps){ e[mm] = 0.0f; lend = mm; break; }
    }
    int l = l1;
    int lsv = l, lendsv = lend;
    l1 = lend + 1;
    if (lend == l) continue;
    float anorm = fabsf(d[l]);
    for (int ii=l+1; ii<=lend; ++ii) anorm = fmaxf(anorm, fabsf(d[ii]));
    for (int ii=l; ii<lend; ++ii)    anorm = fmaxf(anorm, fabsf(e[ii]));
    if (anorm == 0.0f) continue;
    if (fabsf(d[lend]) < fabsf(d[l])){ lend = lsv; l = lendsv; }
    if (lend > l){
      for (;;){
        int m = lend;
        if (l != lend){
          for (int mm=l; mm<=lend-1; ++mm){
            float tst = e[mm]*e[mm];
            if (tst <= (eps2*fabsf(d[mm]))*fabsf(d[mm+1]) + safmin){ m = mm; break; }
          }
        }
        if (m < lend) e[m] = 0.0f;
        float p = d[l];
        if (m == l){
          d[l] = p; ++l;
          if (l <= lend) continue;
          break;
        }
        if (m == l+1){
          float rt1, rt2, c, s;
          slaev2(d[l], e[l], d[l+1], rt1, rt2, c, s);
          #pragma unroll
          for (int r2=0;r2<4;r2++){
            float t_ = z[r2][l+1];
            z[r2][l+1] = c*t_ - s*z[r2][l];
            z[r2][l]   = s*t_ + c*z[r2][l];
          }
          d[l]=rt1; d[l+1]=rt2; e[l]=0.0f;
          l += 2;
          if (l <= lend) continue;
          break;
        }
        if (jtot == nmaxit){ fail = true; break; }
        ++jtot;
        float g = (d[l+1]-p)/(2.0f*e[l]);
        float r_ = slapy2(g, 1.0f);
        g = d[m] - p + e[l]/(g + s_sign(r_, g));
        float s = 1.0f, c = 1.0f;
        p = 0.0f;
        float csv[3], snv[3];
        for (int i=m-1; i>=l; --i){
          float f = s*e[i], b = c*e[i];
          slartg(g, f, c, s, r_);
          if (i != m-1) e[i+1] = r_;
          g = d[i+1] - p;
          r_ = (d[i]-g)*s + 2.0f*c*b;
          p = s*r_;
          d[i+1] = g + p;
          g = c*r_ - b;
          csv[i] = c; snv[i] = -s;
        }
        for (int i=m-1; i>=l; --i){
          float cc = csv[i], ss = snv[i];
          #pragma unroll
          for (int r2=0;r2<4;r2++){
            float t_ = z[r2][i+1];
            z[r2][i+1] = cc*t_ - ss*z[r2][i];
            z[r2][i]   = ss*t_ + cc*z[r2][i];
          }
        }
        d[l] -= p; e[l] = g;
      }
    } else {
      for (;;){
        int m = lend;
        if (l != lend){
          for (int mm=l; mm>=lend+1; --mm){
            float tst = e[mm-1]*e[mm-1];
            if (tst <= (eps2*fabsf(d[mm]))*fabsf(d[mm-1]) + safmin){ m = mm; break; }
          }
        }
        if (m > lend) e[m-1] = 0.0f;
        float p = d[l];
        if (m == l){
          d[l] = p; --l;
          if (l >= lend) continue;
          break;
        }
        if (m == l-1){
          float rt1, rt2, c, s;
          slaev2(d[l-1], e[l-1], d[l], rt1, rt2, c, s);
          #pragma unroll
          for (int r2=0;r2<4;r2++){
            float t_ = z[r2][l];
            z[r2][l]   = c*t_ - s*z[r2][l-1];
            z[r2][l-1] = s*t_ + c*z[r2][l-1];
          }
          d[l-1]=rt1; d[l]=rt2; e[l-1]=0.0f;
          l -= 2;
          if (l >= lend) continue;
          break;
        }
        if (jtot == nmaxit){ fail = true; break; }
        ++jtot;
        float g = (d[l-1]-p)/(2.0f*e[l-1]);
        float r_ = slapy2(g, 1.0f);
        g = d[m] - p + e[l-1]/(g + s_sign(r_, g));
        float s = 1.0f, c = 1.0f;
        p = 0.0f;
        float csv[3], snv[3];
        for (int i=m; i<=l-1; ++i){
          float f = s*e[i], b = c*e[i];
          slartg(g, f, c, s, r_);
          if (i != m) e[i-1] = r_;
          g = d[i] - p;
          r_ = (d[i+1]-g)*s + 2.0f*c*b;
          p = s*r_;
          d[i] = g + p;
          g = c*r_ - b;
          csv[i] = c; snv[i] = s;
        }
        for (int i=m; i<=l-1; ++i){
          float cc = csv[i], ss = snv[i];
          #pragma unroll
          for (int r2=0;r2<4;r2++){
            float t_ = z[r2][i+1];
            z[r2][i+1] = cc*t_ - ss*z[r2][i];
            z[r2][i]   = ss*t_ + cc*z[r2][i];
          }
        }
        d[l] -= p; e[l-1] = g;
      }
    }
  }
  for (int ii=1; ii<4; ++ii){
    int i0 = ii-1, k0 = i0;
    float p = d[i0];
    for (int j2=ii; j2<4; ++j2) if (d[j2] < p){ k0 = j2; p = d[j2]; }
    if (k0 != i0){
      d[k0] = d[i0]; d[i0] = p;
      #pragma unroll
      for (int r2=0;r2<4;r2++){ float t_ = z[r2][i0]; z[r2][i0] = z[r2][k0]; z[r2][k0] = t_; }
    }
  }
  float w0 = z[0][3], w1 = z[1][3], w2 = z[2][3], w3 = z[3][3];
  if (tau1 != 0.0f){
    float dv = w2 + v42*w3;
    w2 -= tau1*dv;
    w3 -= tau1*dv*v42;
  }
  if (tau0 != 0.0f){
    float dv = w1 + v31*w2 + v41*w3;
    w1 -= tau0*dv;
    w2 -= tau0*dv*v31;
    w3 -= tau0*dv*v41;
  }
  q[0]=w0; q[1]=w1; q[2]=w2; q[3]=w3;
}

// ---------------- kernels ----------------
__global__ void fill_kernel(float* __restrict__ p, int nelem, float val){
  int i = blockIdx.x*blockDim.x + threadIdx.x;
  if (i < nelem) p[i] = val;
}

__global__ void rigid_kernel(const float* __restrict__ bb, float* __restrict__ Rg, float* __restrict__ tg){
  int n = blockIdx.x*blockDim.x + threadIdx.x;
  if (n >= NN) return;
  const float* p = bb + (size_t)n*9;
  float nx=p[0],ny=p[1],nz=p[2], cax=p[3],cay=p[4],caz=p[5], cx=p[6],cy=p[7],cz=p[8];
  float e1x=cx-cax, e1y=cy-cay, e1z=cz-caz;
  float n1 = sqrtf(e1x*e1x+e1y*e1y+e1z*e1z);
  e1x/=n1; e1y/=n1; e1z/=n1;
  float ux=nx-cax, uy=ny-cay, uz=nz-caz;
  float du = ux*e1x+uy*e1y+uz*e1z;
  float e2x=ux-du*e1x, e2y=uy-du*e1y, e2z=uz-du*e1z;
  float n2 = sqrtf(e2x*e2x+e2y*e2y+e2z*e2z);
  e2x/=n2; e2y/=n2; e2z/=n2;
  float e3x=e1y*e2z-e1z*e2y, e3y=e1z*e2x-e1x*e2z, e3z=e1x*e2y-e1y*e2x;
  float* R = Rg + (size_t)n*9;
  R[0]=e1x; R[1]=e2x; R[2]=e3x;
  R[3]=e1y; R[4]=e2y; R[5]=e3y;
  R[6]=e1z; R[7]=e2z; R[8]=e3z;
  tg[(size_t)n*3+0]=cax; tg[(size_t)n*3+1]=cay; tg[(size_t)n*3+2]=caz;
}

__global__ __launch_bounds__(256) void ln_kernel(const float* __restrict__ x,
    const float* __restrict__ g, const float* __restrict__ b, float* __restrict__ xln){
  int n = blockIdx.x, t = threadIdx.x;
  __shared__ float rbuf[256];
  float v[5];
  float s = 0.0f;
  #pragma unroll
  for (int i=0;i<5;i++){ v[i] = x[(size_t)n*IND + t + i*256]; s += v[i]; }
  float mu = bsumf(s, rbuf)*(1.0f/IND);
  float pv = 0.0f;
  #pragma unroll
  for (int i=0;i<5;i++){ float dd = v[i]-mu; pv += dd*dd; }
  float var = bsumf(pv, rbuf)*(1.0f/IND);
  float rs = 1.0f/sqrtf(var + 1e-5f);
  #pragma unroll
  for (int i=0;i<5;i++){
    int k = t + i*256;
    xln[(size_t)n*IND + k] = g[k]*((v[i]-mu)*rs) + b[k];
  }
}

// emb0 with LDS staging of the 8 xln rows (arithmetic identical).
__global__ __launch_bounds__(256) void emb0_kernel(const float* __restrict__ xln,
    const float* __restrict__ W, const float* __restrict__ bias, float* __restrict__ emb){
  int n0 = blockIdx.x*8, j = threadIdx.x;
  __shared__ float s_x[8][IND];   // 40 KB
  for (int idx=j; idx<8*IND; idx+=256){
    int i = idx/IND, k = idx - i*IND;
    s_x[i][k] = xln[(size_t)(n0+i)*IND + k];
  }
  __syncthreads();
  float acc[8];
  #pragma unroll
  for (int i=0;i<8;i++) acc[i] = bias[j];
  for (int k=0;k<IND;k+=4){
    float w0=W[(size_t)(k+0)*EMB+j], w1=W[(size_t)(k+1)*EMB+j], w2=W[(size_t)(k+2)*EMB+j], w3=W[(size_t)(k+3)*EMB+j];
    #pragma unroll
    for (int i=0;i<8;i++){
      const float* xp = &s_x[i][k];
      acc[i] += xp[0]*w0 + xp[1]*w1 + xp[2]*w2 + xp[3]*w3;
    }
  }
  #pragma unroll
  for (int i=0;i<8;i++) emb[(size_t)(n0+i)*EMB + j] = acc[i];
}

__global__ __launch_bounds__(64) void edge_kernel(const float* __restrict__ bb,
    const float* __restrict__ Rg, const float* __restrict__ tg,
    const int* __restrict__ col, float* __restrict__ Redge, float* __restrict__ eattr){
  int e = blockIdx.x*64 + threadIdx.x;
  if (e >= EE) return;
  int i = e/KK;
  int jn = col[e];
  float Ri[9], Rj[9];
  #pragma unroll
  for (int a=0;a<9;a++){ Ri[a]=Rg[(size_t)i*9+a]; Rj[a]=Rg[(size_t)jn*9+a]; }
  float dt0 = tg[(size_t)jn*3+0]-tg[(size_t)i*3+0];
  float dt1 = tg[(size_t)jn*3+1]-tg[(size_t)i*3+1];
  float dt2 = tg[(size_t)jn*3+2]-tg[(size_t)i*3+2];
  float Re[9];
  #pragma unroll
  for (int a=0;a<3;a++){
    #pragma unroll
    for (int c=0;c<3;c++)
      Re[a*3+c] = Ri[0+a]*Rj[0+c] + Ri[3+a]*Rj[3+c] + Ri[6+a]*Rj[6+c];
  }
  float te0 = Ri[0]*dt0 + Ri[3]*dt1 + Ri[6]*dt2;
  float te1 = Ri[1]*dt0 + Ri[4]*dt1 + Ri[7]*dt2;
  float te2 = Ri[2]*dt0 + Ri[5]*dt1 + Ri[8]*dt2;
  float xx=Re[0], xy=Re[1], xz=Re[2], yx=Re[3], yy=Re[4], yz=Re[5], zx=Re[6], zy=Re[7], zz=Re[8];
  float km[4][4];
  km[0][0]=(xx+yy+zz)/3.0f; km[0][1]=(zy-yz)/3.0f;    km[0][2]=(xz-zx)/3.0f;    km[0][3]=(yx-xy)/3.0f;
  km[1][0]=km[0][1];        km[1][1]=(xx-yy-zz)/3.0f; km[1][2]=(xy+yx)/3.0f;    km[1][3]=(xz+zx)/3.0f;
  km[2][0]=km[0][2];        km[2][1]=km[1][2];        km[2][2]=(yy-xx-zz)/3.0f; km[2][3]=(yz+zy)/3.0f;
  km[3][0]=km[0][3];        km[3][1]=km[1][3];        km[3][2]=km[2][3];        km[3][3]=(zz-xx-yy)/3.0f;
  float q[4];
  sym4_quat_f32(km, q);
  float* ea = eattr + (size_t)e*EAP;
  ea[0]=q[0]; ea[1]=q[1]; ea[2]=q[2]; ea[3]=q[3];
  ea[4]=te0;  ea[5]=te1;  ea[6]=te2;
  int cd = i - jn; if (cd < 0) cd = -cd;
  ea[7] = logf((float)cd + 1.0f);
  ea[8] = logf(sqrtf(te0*te0+te1*te1+te2*te2) + 1e-8f);
  const float* bi = bb + (size_t)i*9;
  const float* bj = bb + (size_t)jn*9;
  int idx = 9;
  #pragma unroll
  for (int a=0;a<3;a++){
    float ax=bi[a*3+0], ay=bi[a*3+1], az=bi[a*3+2];
    #pragma unroll
    for (int b2=0;b2<3;b2++){
      float dx=ax-bj[b2*3+0], dy=ay-bj[b2*3+1], dz=az-bj[b2*3+2];
      float dd = sqrtf(fmaxf(dx*dx+dy*dy+dz*dz, 1e-12f));
      #pragma unroll
      for (int kb=0;kb<16;kb++){
        float muv = 1.3333334f*(float)kb;
        float df = dd - muv;
        ea[idx] = expf(-0.5f*df*df);
        idx++;
      }
    }
  }
  ea[153]=0.0f; ea[154]=0.0f; ea[155]=0.0f;
  #pragma unroll
  for (int a=0;a<9;a++) Redge[(size_t)e*9+a] = Re[a];
}

// Fused h1 + h2 + LN + vu per node-block. Arithmetic bit-identical to R9.
// LDS layout change only: sbuf/rbuf union'd into the phase-B-only s_ea region
// so total LDS = 52448 B < 54613 -> 3 blocks/CU.
__global__ __launch_bounds__(256, 3) void fused_kernel(
    const float* __restrict__ emb_in, const float* __restrict__ v_in,
    const float* __restrict__ Redge, const float* __restrict__ eattr,
    const int* __restrict__ col,
    const float* __restrict__ W1, const float* __restrict__ b1,
    const float* __restrict__ W2, const float* __restrict__ b2,
    const float* __restrict__ W3, const float* __restrict__ b3,
    const float* __restrict__ vW,
    const float* __restrict__ lng, const float* __restrict__ lnb,
    float* __restrict__ emb_out, float* __restrict__ vu_out){
  int n = blockIdx.x, j = threadIdx.x;
  size_t e0 = (size_t)n*KK;
  __shared__ float s_big[KK*EMB];     // 30720 B: s_emb (phase B), s_h1 (phase C)
  __shared__ float s_eau[KK*EAP];     // 18720 B: eattr (phase B); sbuf/rbuf (phase C)
  __shared__ float s_vjr[KK][16];     // 1920 B
  __shared__ float s_xi [EMB];        // 1024 B
  __shared__ float s_vi [16];         // 64 B
  float* sbuf = s_eau;                // phase C alias (disjoint in time from eattr use)
  float* rbuf = s_eau + 256;          // phase C alias

  // ---- staging (coalesced) ----
  #pragma unroll
  for (int e=0;e<KK;e++){
    int cj = col[e0+e];
    s_big[e*EMB + j] = emb_in[(size_t)cj*EMB + j];
  }
  s_xi[j] = emb_in[(size_t)n*EMB + j];
  if (j < V3) s_vi[j] = v_in[(size_t)n*V3 + j];
  for (int idx=j; idx<KK*EAP; idx+=256){
    s_eau[idx] = eattr[e0*EAP + idx];
  }
  // inlined vjr (same expression as original vjr_kernel)
  for (int idx=j; idx<KK*16; idx+=256){
    int e = idx>>4, r = idx&15;
    if (r < V3){
      int m = r/3, ii = r - m*3;
      int cj = col[e0+e];
      const float* Rp = Redge + (e0+e)*9;
      const float* vp = v_in + (size_t)cj*V3 + m*3;
      s_vjr[e][r] = Rp[ii*3+0]*vp[0] + Rp[ii*3+1]*vp[1] + Rp[ii*3+2]*vp[2];
    }
  }
  __syncthreads();

  // ---- phase B: h1 ----
  float csh = b1[j];
  {
    for (int k=0;k<EMB;k+=4){
      float w0=W1[(size_t)(k+0)*EMB+j], w1=W1[(size_t)(k+1)*EMB+j], w2=W1[(size_t)(k+2)*EMB+j], w3=W1[(size_t)(k+3)*EMB+j];
      csh += s_xi[k+0]*w0 + s_xi[k+1]*w1 + s_xi[k+2]*w2 + s_xi[k+3]*w3;
    }
    #pragma unroll
    for (int r=0;r<V3;r++) csh += s_vi[r]*(W1[(size_t)(512+r)*EMB+j] + W1[(size_t)(542+r)*EMB+j]);
  }
  float acc[KK];
  #pragma unroll
  for (int e=0;e<KK;e++) acc[e] = csh;
  #pragma unroll
  for (int eg=0; eg<KK; eg+=15){
    for (int k=0;k<EMB;k+=4){
      float w0=W1[(size_t)(256+k)*EMB+j], w1=W1[(size_t)(257+k)*EMB+j], w2=W1[(size_t)(258+k)*EMB+j], w3=W1[(size_t)(259+k)*EMB+j];
      #pragma unroll
      for (int qq=0;qq<15;qq++){
        const float* xp = &s_big[(eg+qq)*EMB + k];
        acc[eg+qq] += xp[0]*w0 + xp[1]*w1 + xp[2]*w2 + xp[3]*w3;
      }
    }
  }
  {
    float wv[V3];
    #pragma unroll
    for (int r=0;r<V3;r++) wv[r] = W1[(size_t)(527+r)*EMB+j] - W1[(size_t)(542+r)*EMB+j];
    #pragma unroll
    for (int e=0;e<KK;e++){
      float a = acc[e];
      #pragma unroll
      for (int r=0;r<V3;r++) a += s_vjr[e][r]*wv[r];
      acc[e] = a;
    }
  }
  #pragma unroll
  for (int eg=0; eg<KK; eg+=15){
    for (int k=0;k<152;k+=4){
      float w0=W1[(size_t)(557+k)*EMB+j], w1=W1[(size_t)(558+k)*EMB+j], w2=W1[(size_t)(559+k)*EMB+j], w3=W1[(size_t)(560+k)*EMB+j];
      #pragma unroll
      for (int qq=0;qq<15;qq++){
        const float* ap = &s_eau[(eg+qq)*EAP + k];
        acc[eg+qq] += ap[0]*w0 + ap[1]*w1 + ap[2]*w2 + ap[3]*w3;
      }
    }
    float wl = W1[(size_t)709*EMB+j];
    #pragma unroll
    for (int qq=0;qq<15;qq++) acc[eg+qq] += s_eau[(eg+qq)*EAP + 152]*wl;
  }
  // h1 -> LDS (reuse s_big)
  __syncthreads();
  #pragma unroll
  for (int e=0;e<KK;e++) s_big[e*EMB + j] = gelu_f(acc[e]);
  __syncthreads();   // also fences last s_eau(eattr) reads before alias reuse

  // ---- phase C: h2 ----
  float acc2[KK];
  #pragma unroll
  for (int e=0;e<KK;e++) acc2[e] = b2[j];
  #pragma unroll
  for (int eg=0; eg<KK; eg+=15){
    for (int k=0;k<EMB;k+=4){
      float w0=W2[(size_t)(k+0)*EMB+j], w1=W2[(size_t)(k+1)*EMB+j], w2=W2[(size_t)(k+2)*EMB+j], w3=W2[(size_t)(k+3)*EMB+j];
      #pragma unroll
      for (int qq=0;qq<15;qq++){
        const float* hp = &s_big[(eg+qq)*EMB + k];
        acc2[eg+qq] += hp[0]*w0 + hp[1]*w1 + hp[2]*w2 + hp[3]*w3;
      }
    }
  }
  float s = 0.0f;
  #pragma unroll
  for (int e=0;e<KK;e++) s += gelu_f(acc2[e]);
  __syncthreads();   // ensure all phase-B eattr reads done before sbuf alias write
  sbuf[j] = s;
  __syncthreads();
  float ag = 0.0f;
  for (int k=0;k<EMB;k+=4){
    float4 s4 = *(const float4*)&sbuf[k];
    ag += s4.x*W3[(size_t)(k+0)*EMB+j] + s4.y*W3[(size_t)(k+1)*EMB+j]
        + s4.z*W3[(size_t)(k+2)*EMB+j] + s4.w*W3[(size_t)(k+3)*EMB+j];
  }
  ag = ag*(1.0f/30.0f) + b3[j];
  float u = s_xi[j] + ag;            // s_xi[j] == emb_in[n*EMB+j] (staged)
  float mu = bsumf(u, rbuf)*(1.0f/EMB);
  float dl = u - mu;
  float var = bsumf(dl*dl, rbuf)*(1.0f/EMB);
  float rs = 1.0f/sqrtf(var + 1e-5f);
  float y = lng[j]*dl*rs + lnb[j];
  emb_out[(size_t)n*EMB+j] = y;
  __syncthreads();   // all reads of sbuf (W3 dot) complete before overwrite
  sbuf[j] = y;
  __syncthreads();
  // ---- vu ----
  if (j < V3){
    float a = s_vi[j];
    for (int k=0;k<EMB;k++){
      a += sbuf[k]*vW[k*V3+j];
    }
    #pragma unroll
    for (int r=0;r<V3;r++) a += s_vi[r]*vW[(EMB+r)*V3+j];
    vu_out[(size_t)n*V3+j] = a;
  }
}

// Pure QR per graph (f32 sgeqr2/sorg2r, raw LAPACK signs) — untouched.
__global__ __launch_bounds__(256) void qr_kernel(
    const float* __restrict__ vu_in, float* __restrict__ vout){
  int g = blockIdx.x, t = threadIdx.x;
  __shared__ float A[QRM*QRN];
  __shared__ float meanv[V3];
  __shared__ float taus[QRN];
  __shared__ float sh[2];
  int n = g*LSZ + t;
  #pragma unroll
  for (int j=0;j<V3;j++) A[t*V3+j] = vu_in[(size_t)n*V3 + j];
  __syncthreads();
  if (t < V3){
    float s = 0.0f;
    for (int l0=0;l0<LSZ;l0++) s += A[l0*V3+t];
    meanv[t] = s/(float)LSZ;
  }
  __syncthreads();
  #pragma unroll
  for (int j=0;j<V3;j++) A[t*V3+j] -= meanv[j];
  __syncthreads();
  // ---- sgeqr2 ----
  for (int i=0;i<QRN;i++){
    if (t == 0){
      float s0=0,s1=0,s2=0,s3=0;
      int r=i+1;
      for (; r+3<QRM; r+=4){
        float x0=A[r*QRN+i], x1=A[(r+1)*QRN+i], x2=A[(r+2)*QRN+i], x3=A[(r+3)*QRN+i];
        s0+=x0*x0; s1+=x1*x1; s2+=x2*x2; s3+=x3*x3;
      }
      for (; r<QRM; r++){ float x=A[r*QRN+i]; s0+=x*x; }
      float xn2 = (s0+s1)+(s2+s3);
      float alpha = A[i*QRN+i];
      float taui = 0.0f, sc = 1.0f;
      if (xn2 != 0.0f){
        float beta = -s_sign(slapy2(alpha, sqrtf(xn2)), alpha);
        taui = (beta - alpha)/beta;
        sc = 1.0f/(alpha - beta);
      }
      taus[i] = taui; sh[0] = sc;
    }
    __syncthreads();
    {
      float sc = sh[0];
      for (int r=i+1+t; r<QRM; r+=256) A[r*QRN+i] *= sc;
    }
    __syncthreads();
    for (int j=i+1;j<QRN;j++){
      if (t == 0){
        float s0=A[i*QRN+j], s1=0,s2=0,s3=0;
        int r=i+1;
        for (; r+3<QRM; r+=4){
          s0 += A[r*QRN+i]*A[r*QRN+j];
          s1 += A[(r+1)*QRN+i]*A[(r+1)*QRN+j];
          s2 += A[(r+2)*QRN+i]*A[(r+2)*QRN+j];
          s3 += A[(r+3)*QRN+i]*A[(r+3)*QRN+j];
        }
        for (; r<QRM; r++) s0 += A[r*QRN+i]*A[r*QRN+j];
        sh[0] = taus[i]*((s0+s1)+(s2+s3));
      }
      __syncthreads();
      {
        float w = sh[0];
        for (int r=i+t; r<QRM; r+=256){
          float vr = (r==i) ? 1.0f : A[r*QRN+i];
          A[r*QRN+j] -= w*vr;
        }
      }
      __syncthreads();
    }
  }
  // ---- sorg2r ----
  for (int i=QRN-1;i>=0;i--){
    for (int j=i+1;j<QRN;j++){
      if (t == 0){
        float s0=A[i*QRN+j], s1=0,s2=0,s3=0;
        int r=i+1;
        for (; r+3<QRM; r+=4){
          s0 += A[r*QRN+i]*A[r*QRN+j];
          s1 += A[(r+1)*QRN+i]*A[(r+1)*QRN+j];
          s2 += A[(r+2)*QRN+i]*A[(r+2)*QRN+j];
          s3 += A[(r+3)*QRN+i]*A[(r+3)*QRN+j];
        }
        for (; r<QRM; r++) s0 += A[r*QRN+i]*A[r*QRN+j];
        sh[0] = taus[i]*((s0+s1)+(s2+s3));
      }
      __syncthreads();
      {
        float w = sh[0];
        for (int r=i+t; r<QRM; r+=256){
          float vr = (r==i) ? 1.0f : A[r*QRN+i];
          A[r*QRN+j] -= w*vr;
        }
      }
      __syncthreads();
    }
    {
      float taui = taus[i];
      for (int r=i+1+t; r<QRM; r+=256) A[r*QRN+i] *= -taui;
    }
    __syncthreads();
    if (t == 0) A[i*QRN+i] = 1.0f - taus[i];
    if (t < i) A[t*QRN+i] = 0.0f;
    __syncthreads();
  }
  for (int idx=t; idx<QRM*QRN; idx+=256)
    vout[(size_t)g*LSZ*V3 + idx] = 16.0f*A[idx];
}

__global__ __launch_bounds__(256) void final_kernel(const float* __restrict__ embf,
    const float* __restrict__ vf, const float* __restrict__ Rg, float* __restrict__ out){
  int n = blockIdx.x, t = threadIdx.x;
  out[(size_t)n*EMB + t] = embf[(size_t)n*EMB + t];
  if (t < V3){
    int m = t/3, ii = t - m*3;
    const float* Rp = Rg + (size_t)n*9;
    const float* vp = vf + (size_t)n*V3 + m*3;
    float val = Rp[ii*3+0]*vp[0] + Rp[ii*3+1]*vp[1] + Rp[ii*3+2]*vp[2];
    out[(size_t)NN*EMB + (size_t)n*V3 + t] = val;
  }
}

// ---------------- host ----------------
extern "C" void kernel_launch(void* const* d_in, const int* in_sizes, int n_in,
                              void* d_out, int out_size, void* d_ws, size_t ws_size,
                              hipStream_t stream){
  (void)in_sizes; (void)n_in; (void)out_size; (void)ws_size;
  const float* x       = (const float*)d_in[0];
  const float* bb      = (const float*)d_in[1];
  const float* in_ln_g = (const float*)d_in[2];
  const float* in_ln_b = (const float*)d_in[3];
  const float* in_W    = (const float*)d_in[4];
  const float* in_b    = (const float*)d_in[5];
  const float* msg_W1  = (const float*)d_in[6];
  const float* msg_b1  = (const float*)d_in[7];
  const float* msg_W2  = (const float*)d_in[8];
  const float* msg_b2  = (const float*)d_in[9];
  const float* msg_W3  = (const float*)d_in[10];
  const float* msg_b3  = (const float*)d_in[11];
  const float* vect_W  = (const float*)d_in[12];
  const float* ln_g    = (const float*)d_in[13];
  const float* ln_b    = (const float*)d_in[14];
  const int*   col     = (const int*)d_in[16];

  char* p = (char*)d_ws;
  auto alloc = [&](size_t bytes)->void*{ void* r = (void*)p; p += (bytes + 255) & ~(size_t)255; return r; };
  float*  Rg    = (float*) alloc((size_t)NN*9*4);
  float*  tg    = (float*) alloc((size_t)NN*3*4);
  float*  xln   = (float*) alloc((size_t)NN*IND*4);
  float*  eA    = (float*) alloc((size_t)NN*EMB*4);
  float*  eB    = (float*) alloc((size_t)NN*EMB*4);
  float*  vA    = (float*) alloc((size_t)NN*V3*4);
  float*  vB    = (float*) alloc((size_t)NN*V3*4);
  float*  vu    = (float*) alloc((size_t)NN*V3*4);
  float*  Redge = (float*) alloc((size_t)EE*9*4);
  float*  eattr = (float*) alloc((size_t)EE*EAP*4);

  const int NV = NN*V3;
  fill_kernel<<<(NV+255)/256, 256, 0, stream>>>(vA, NV, 0.0f);
  rigid_kernel<<<(NN+63)/64, 64, 0, stream>>>(bb, Rg, tg);
  ln_kernel<<<NN, 256, 0, stream>>>(x, in_ln_g, in_ln_b, xln);
  emb0_kernel<<<NN/8, 256, 0, stream>>>(xln, in_W, in_b, eA);
  edge_kernel<<<(EE+63)/64, 64, 0, stream>>>(bb, Rg, tg, col, Redge, eattr);

  float* ein = eA; float* eout = eB; float* vin = vA; float* vout = vB;
  for (int l=0; l<3; ++l){
    fused_kernel<<<NN, 256, 0, stream>>>(ein, vin, Redge, eattr, col,
        msg_W1 + (size_t)l*710*EMB, msg_b1 + (size_t)l*EMB,
        msg_W2 + (size_t)l*EMB*EMB, msg_b2 + (size_t)l*EMB,
        msg_W3 + (size_t)l*EMB*EMB, msg_b3 + (size_t)l*EMB,
        vect_W + (size_t)l*(EMB+V3)*V3,
        ln_g + (size_t)l*EMB, ln_b + (size_t)l*EMB, eout, vu);
    qr_kernel<<<NG, 256, 0, stream>>>(vu, vout);
    float* tmp = ein; ein = eout; eout = tmp;
    tmp = vin; vin = vout; vout = tmp;
  }
  final_kernel<<<NN, 256, 0, stream>>>(ein, vin, Rg, (float*)d_out);
}